// Round 9
// baseline (3841.570 us; speedup 1.0000x reference)
//
#include <hip/hip_runtime.h>
#include <stdint.h>

// ---------------------------------------------------------------------------
// GRUClassifier round 16: unbundle round 15. GRU path reverted to the
// VERIFIED round-14 structure byte-for-byte (every structural change to the
// asm-load/wait cluster has failed: r10/11/12/15 -> NaN; pure compiler-load
// additions r13/r14 -> pass). Keep only round 15's change (B): attention
// la/sa weight tiles (64x16B/thread, loop-invariant) hoisted into registers
// (lawr[3][16], sawr[16], statically indexed, compiler loads, same ascending
// kc accumulation order as r14's unroll-2 loop -> bit-identical numerics).
// Outcome decision tree: pass -> r15 NaN was the GRU two-phase (never touch
// wait structure again); NaN -> hoist implicated, revert to r14 and close.
// Canaries: absmax 0.00390625 exactly; WRITE_SIZE ~4.0e5 KB; conflicts ~4.1e8.
// ---------------------------------------------------------------------------

typedef short short8 __attribute__((ext_vector_type(8)));
typedef float floatx4 __attribute__((ext_vector_type(4)));
typedef int intx4 __attribute__((ext_vector_type(4)));
typedef unsigned long long u64;

#define NB 512
#define NT 256
#define NH 256
#define NG 768
#define R_RING 8
#define RSLOT (6 * NB * NH)          // u16 elems per ring slot
#define BTH 256

__device__ __forceinline__ float bf2f(uint16_t v) {
    uint32_t u = ((uint32_t)v) << 16;
    float f;
    __builtin_memcpy(&f, &u, 4);
    return f;
}
__device__ __forceinline__ uint16_t f2bf(float f) {
    uint32_t u;
    __builtin_memcpy(&u, &f, 4);
    uint32_t r = (u + 0x7FFFu + ((u >> 16) & 1u)) >> 16;
    return (uint16_t)r;
}
__device__ __forceinline__ u64 pack4bf(float4 v) {
    u64 a = f2bf(v.x), b = f2bf(v.y), c = f2bf(v.z), d = f2bf(v.w);
    return a | (b << 16) | (c << 32) | (d << 48);
}
__device__ __forceinline__ float sigmoidf_(float x) { return 1.f / (1.f + expf(-x)); }
__device__ __forceinline__ float geluf_(float x) { return 0.5f * x * (1.f + erff(x * 0.70710678118f)); }
__device__ __forceinline__ short8 as_s8(intx4 v) { short8 r; __builtin_memcpy(&r, &v, 16); return r; }

// two write-through 16B stores + own-thread drain
__device__ __forceinline__ void st2_coh16_wait(void* p0, intx4 v0, void* p1, intx4 v1) {
    asm volatile("global_store_dwordx4 %0, %1, off sc0 sc1\n\t"
                 "global_store_dwordx4 %2, %3, off sc0 sc1\n\t"
                 "s_waitcnt vmcnt(0)"
                 :: "v"(p0), "v"(v0), "v"(p1), "v"(v1) : "memory");
}

// 8 coherent loads from one plane-base (SGPR) with per-lane 32-bit offsets
__device__ __forceinline__ void ld_plane8(u64 sbase,
    uint32_t o0, uint32_t o1, uint32_t o2, uint32_t o3,
    uint32_t o4, uint32_t o5, uint32_t o6, uint32_t o7, intx4* v) {
    asm volatile(
        "global_load_dwordx4 %0, %8, %16 sc0 sc1\n\t"
        "global_load_dwordx4 %1, %9, %16 sc0 sc1\n\t"
        "global_load_dwordx4 %2, %10, %16 sc0 sc1\n\t"
        "global_load_dwordx4 %3, %11, %16 sc0 sc1\n\t"
        "global_load_dwordx4 %4, %12, %16 sc0 sc1\n\t"
        "global_load_dwordx4 %5, %13, %16 sc0 sc1\n\t"
        "global_load_dwordx4 %6, %14, %16 sc0 sc1\n\t"
        "global_load_dwordx4 %7, %15, %16 sc0 sc1"
        : "=&v"(v[0]), "=&v"(v[1]), "=&v"(v[2]), "=&v"(v[3]),
          "=&v"(v[4]), "=&v"(v[5]), "=&v"(v[6]), "=&v"(v[7])
        : "v"(o0), "v"(o1), "v"(o2), "v"(o3), "v"(o4), "v"(o5), "v"(o6), "v"(o7),
          "s"(sbase)
        : "memory");
}
// drain all outstanding vmem; ties 8 values so their uses can't be hoisted
__device__ __forceinline__ void wait_vm8(intx4* v) {
    asm volatile("s_waitcnt vmcnt(0)"
                 : "+v"(v[0]), "+v"(v[1]), "+v"(v[2]), "+v"(v[3]),
                   "+v"(v[4]), "+v"(v[5]), "+v"(v[6]), "+v"(v[7])
                 :: "memory");
}
// 12 scattered coherent loads (attention staging, 256-thread blocks)
__device__ __forceinline__ void ld_sc12(
    const uint16_t* p0, const uint16_t* p1, const uint16_t* p2,
    const uint16_t* p3, const uint16_t* p4, const uint16_t* p5,
    const uint16_t* p6, const uint16_t* p7, const uint16_t* p8,
    const uint16_t* p9, const uint16_t* p10, const uint16_t* p11, intx4* v) {
    asm volatile(
        "global_load_dwordx4 %0, %12, off sc0 sc1\n\t"
        "global_load_dwordx4 %1, %13, off sc0 sc1\n\t"
        "global_load_dwordx4 %2, %14, off sc0 sc1\n\t"
        "global_load_dwordx4 %3, %15, off sc0 sc1\n\t"
        "global_load_dwordx4 %4, %16, off sc0 sc1\n\t"
        "global_load_dwordx4 %5, %17, off sc0 sc1\n\t"
        "global_load_dwordx4 %6, %18, off sc0 sc1\n\t"
        "global_load_dwordx4 %7, %19, off sc0 sc1\n\t"
        "global_load_dwordx4 %8, %20, off sc0 sc1\n\t"
        "global_load_dwordx4 %9, %21, off sc0 sc1\n\t"
        "global_load_dwordx4 %10, %22, off sc0 sc1\n\t"
        "global_load_dwordx4 %11, %23, off sc0 sc1\n\t"
        "s_waitcnt vmcnt(0)"
        : "=&v"(v[0]), "=&v"(v[1]), "=&v"(v[2]), "=&v"(v[3]),
          "=&v"(v[4]), "=&v"(v[5]), "=&v"(v[6]), "=&v"(v[7]),
          "=&v"(v[8]), "=&v"(v[9]), "=&v"(v[10]), "=&v"(v[11])
        : "v"(p0), "v"(p1), "v"(p2), "v"(p3), "v"(p4), "v"(p5),
          "v"(p6), "v"(p7), "v"(p8), "v"(p9), "v"(p10), "v"(p11)
        : "memory");
}

#define PIDX(s, t, bt) ((((s) * NT) + (t)) * 4 + (bt))

// ---------------- small utility kernels ------------------------------------
__global__ void k_cvt(const float* __restrict__ src, uint16_t* __restrict__ dst, int n4) {
    int i = blockIdx.x * blockDim.x + threadIdx.x;
    if (i < n4) {
        float4 v = ((const float4*)src)[i];
        ushort4 o;
        o.x = f2bf(v.x); o.y = f2bf(v.y); o.z = f2bf(v.z); o.w = f2bf(v.w);
        ((ushort4*)dst)[i] = o;
    }
}
__global__ void k_zero(float* __restrict__ p, int n4) {
    int i = blockIdx.x * blockDim.x + threadIdx.x;
    if (i < n4) ((float4*)p)[i] = make_float4(0.f, 0.f, 0.f, 0.f);
}
__global__ void k_sentinel(float* __restrict__ out) {
    int i = blockIdx.x * blockDim.x + threadIdx.x;
    if (i < 1024) out[i] = -99999.0f;
}

// ---------------- encoder: encoded = mish(x @ enc_w^T + enc_b), bf16 out ----
__global__ __launch_bounds__(256) void k_encoder(
    const float* __restrict__ x, const float* __restrict__ enc_w,
    const float* __restrict__ enc_b, uint16_t* __restrict__ enc_out) {
    const int tid = threadIdx.x;
    const int lane = tid & 63, wid = tid >> 6;
    const int q = lane >> 4, l15 = lane & 15;
    const int wm = wid >> 1, wj = wid & 1;
    const int j0 = blockIdx.x * 128, b0 = blockIdx.y * 128;

    __shared__ uint16_t a_s[128 * 72];
    __shared__ uint16_t w_s[128 * 72];

#pragma unroll
    for (int jj = 0; jj < 8; ++jj) {
        int u = tid + jj * 256;
        int r = u >> 4, c4 = (u & 15) * 4;
        float4 va = *(const float4*)&x[(size_t)(b0 + r) * 64 + c4];
        float4 vw = *(const float4*)&enc_w[(size_t)(j0 + r) * 64 + c4];
        *(u64*)&a_s[r * 72 + c4] = pack4bf(va);
        *(u64*)&w_s[r * 72 + c4] = pack4bf(vw);
    }
    __syncthreads();

    floatx4 acc[4][4];
#pragma unroll
    for (int mi = 0; mi < 4; ++mi)
#pragma unroll
        for (int nf = 0; nf < 4; ++nf) acc[mi][nf] = (floatx4){0.f, 0.f, 0.f, 0.f};

#pragma unroll
    for (int kc = 0; kc < 2; ++kc) {
        short8 af[4], bfg[4];
#pragma unroll
        for (int mi = 0; mi < 4; ++mi)
            af[mi] = *(const short8*)&a_s[(wm * 64 + mi * 16 + l15) * 72 + kc * 32 + q * 8];
#pragma unroll
        for (int nf = 0; nf < 4; ++nf)
            bfg[nf] = *(const short8*)&w_s[(wj * 64 + nf * 16 + l15) * 72 + kc * 32 + q * 8];
#pragma unroll
        for (int mi = 0; mi < 4; ++mi)
#pragma unroll
            for (int nf = 0; nf < 4; ++nf)
                acc[mi][nf] = __builtin_amdgcn_mfma_f32_16x16x32_bf16(af[mi], bfg[nf], acc[mi][nf], 0, 0, 0);
    }

#pragma unroll
    for (int nf = 0; nf < 4; ++nf) {
        int j = j0 + wj * 64 + nf * 16 + l15;
        float eb = enc_b[j];
#pragma unroll
        for (int mi = 0; mi < 4; ++mi)
#pragma unroll
            for (int r = 0; r < 4; ++r) {
                int b = b0 + wm * 64 + mi * 16 + q * 4 + r;
                float v = acc[mi][nf][r] + eb;
                float sp = (v > 20.f) ? v : log1pf(expf(v));
                float m = v * tanhf(sp);
                enc_out[(size_t)b * 32768 + j] = f2bf(m);
            }
    }
}

// ---------------- shared memory layouts ------------------------------------
struct SGru {
    uint16_t wgi[96 * 520];   // [3g*32r][K(+8 pad)]  (row-major, round-9 layout)
    uint16_t h_out[128 * 32]; // publish staging
};
struct SAtt {
    uint16_t hbf[6 * 16 * 264];
    float laP[3][3][16];
    float saT[4][16][17];
    float s_s[16], lg_s[16];
};
union SMem { SGru g; SAtt a; };

// ---------------- pipelined scan kernel ------------------------------------
// grid 224 x 256 thr.
//  b<192: GRU block: sd=b>>5, es=(b&31)>>2 (8 e-slices of 32), bt=b&3.
//         4 waves x 32 rows; gh weights in registers; gi weights in LDS.
//         (wait/load structure byte-identical to verified round 14)
//  b>=192: attention block ab=b-192 (32 blocks of 16 rows), 4 waves;
//         la/sa weights register-cached (loop-invariant hoist).
// Ring layout: slot[(t&7)] . plane[sd*8+es] (32KB) . row (64B) . col16.
__global__ __launch_bounds__(BTH, 1) void k_scan(
    const uint16_t* __restrict__ enc_bf,
    const uint16_t* __restrict__ wih0_bf, const uint16_t* __restrict__ wihL_bf,
    const uint16_t* __restrict__ whh_bf,
    const float* __restrict__ bih, const float* __restrict__ bhh,
    const uint16_t* __restrict__ law1_bf, const float* __restrict__ la_b1,
    const float* __restrict__ la_w2, const float* __restrict__ la_b2,
    const uint16_t* __restrict__ saw1_bf, const float* __restrict__ sa_b1,
    const float* __restrict__ sa_w2, const float* __restrict__ sa_b2,
    const float* __restrict__ ln_g, const float* __restrict__ ln_b,
    const float* __restrict__ fc_w, const float* __restrict__ fc_b,
    uint16_t* __restrict__ ring, int* produced, int* consumed,
    float* __restrict__ out) {
    const int blk = blockIdx.x;
    const int tid = threadIdx.x;
    const int w = tid >> 6;          // 0..3
    const int lane = tid & 63;
    const int q = lane >> 4, l15 = lane & 15;

    __shared__ SMem sm;

    if (blk < 192) {
        // =================== GRU stage block (== round 14) =================
        const int sd = blk >> 5;
        const int l = sd >> 1, dd = sd & 1;
        const int rem = blk & 31;
        const int es = rem >> 2;
        const int bt = rem & 3;
        const int row0 = bt * 128;
        const int Kgi = (l == 0) ? 128 : 512;
        const int ksh = (l == 0) ? 7 : 9;
        const int strgi = Kgi + 8;
        const uint16_t* wih = (l == 0) ? wih0_bf + (size_t)dd * NG * 128
                                       : wihL_bf + (size_t)((l - 1) * 2 + dd) * NG * 512;
        const uint16_t* whhp = whh_bf + (size_t)sd * NG * 256;
        const int ncons = (l < 2) ? 32 : 16;

        // ---- load gi weights into LDS (once), row-major round-9 layout ----
        for (int flat = tid * 8; flat < 96 * Kgi; flat += BTH * 8) {
            int r = flat >> ksh, c = flat & (Kgi - 1);
            int g = r >> 5, rr = r & 31;
            int srow = g * 256 + es * 32 + rr;
            *(intx4*)&sm.g.wgi[r * strgi + c] = *(const intx4*)&wih[(size_t)srow * Kgi + c];
        }
        // ---- gh weights: registers, loaded ONCE from global (r13/r14). ----
        short8 wghr[2][3][8];
#pragma unroll
        for (int sub = 0; sub < 2; ++sub)
#pragma unroll
            for (int g = 0; g < 3; ++g)
#pragma unroll
                for (int kc = 0; kc < 8; ++kc)
                    wghr[sub][g][kc] = *(const short8*)&whhp[
                        (size_t)(g * 256 + es * 32 + sub * 16 + l15) * 256 + kc * 32 + q * 8];

        float bRs[2], bZs[2], bNs[2], bHNs[2];
        {
            int ba = sd * NG;
#pragma unroll
            for (int sub = 0; sub < 2; ++sub) {
                int e = es * 32 + sub * 16 + l15;
                bRs[sub] = bih[ba + e] + bhh[ba + e];
                bZs[sub] = bih[ba + 256 + e] + bhh[ba + 256 + e];
                bNs[sub] = bih[ba + 512 + e];
                bHNs[sub] = bhh[ba + 512 + e];
            }
        }
        int wofs_gi[2][3];
#pragma unroll
        for (int sub = 0; sub < 2; ++sub)
#pragma unroll
            for (int g = 0; g < 3; ++g)
                wofs_gi[sub][g] = (g * 32 + sub * 16 + l15) * strgi + q * 8;
        // fp32 hidden carry: hreg[mt][sub][r], rows w*32 + mt*16 + q*4 + r
        float hreg[2][2][4];
#pragma unroll
        for (int mt = 0; mt < 2; ++mt)
#pragma unroll
            for (int sub = 0; sub < 2; ++sub)
#pragma unroll
                for (int r = 0; r < 4; ++r) hreg[mt][sub][r] = 0.f;

        const int myrowA = row0 + w * 32 + l15;     // A-tile 0 row; tile 1 = +16
        // loop-invariant per-lane plane offsets (bytes): kc*32KB + row*64 + q*16
        uint32_t voA[8], voB[8];
#pragma unroll
        for (int kc = 0; kc < 8; ++kc) {
            voA[kc] = (uint32_t)(kc * 32768 + myrowA * 64 + q * 16);
            voB[kc] = voA[kc] + 1024;               // +16 rows
        }
        const u64 ring_u = (u64)(uintptr_t)ring;
        __syncthreads();

        for (int t = 0; t < NT; ++t) {
            // ---- waits (thread 0): back-pressure, own t-1, upstream t ----
            if (tid == 0) {
                if (t >= R_RING) {
                    const int* cp = &consumed[PIDX(sd, t - R_RING, bt)];
                    while (__hip_atomic_load(cp, __ATOMIC_RELAXED, __HIP_MEMORY_SCOPE_AGENT) < ncons)
                        __builtin_amdgcn_s_sleep(1);
                }
                if (t >= 1) {
                    const int* sp = &produced[PIDX(sd, t - 1, bt)];
                    while (__hip_atomic_load(sp, __ATOMIC_RELAXED, __HIP_MEMORY_SCOPE_AGENT) < 8)
                        __builtin_amdgcn_s_sleep(1);
                }
                if (l > 0) {
                    const int* p0 = &produced[PIDX(2 * (l - 1), t, bt)];
                    const int* p1 = &produced[PIDX(2 * (l - 1) + 1, t, bt)];
                    while (__hip_atomic_load(p0, __ATOMIC_RELAXED, __HIP_MEMORY_SCOPE_AGENT) < 8)
                        __builtin_amdgcn_s_sleep(1);
                    while (__hip_atomic_load(p1, __ATOMIC_RELAXED, __HIP_MEMORY_SCOPE_AGENT) < 8)
                        __builtin_amdgcn_s_sleep(1);
                }
            }
            __syncthreads();

            // ---- A-fragment loads (all STATIC av indices -> registers) ----
            // av[0..7]=gh mt0, av[8..15]=gh mt1,
            // av[16..31]=gi mt0, av[32..47]=gi mt1
            intx4 av[48];
            const u64 sb_gh = ring_u + (u64)((t - 1) & 7) * (RSLOT * 2) + ((u64)(sd * 8) << 15);
            if (l > 0) {
                const u64 sb0 = ring_u + (u64)(t & 7) * (RSLOT * 2) + ((u64)((2 * l - 2) * 8) << 15);
                if (t > 0) {
                    ld_plane8(sb_gh, voA[0], voA[1], voA[2], voA[3], voA[4], voA[5], voA[6], voA[7], av);
                    ld_plane8(sb_gh, voB[0], voB[1], voB[2], voB[3], voB[4], voB[5], voB[6], voB[7], av + 8);
                } else {
#pragma unroll
                    for (int i = 0; i < 16; ++i) av[i] = (intx4){0, 0, 0, 0};
                }
                ld_plane8(sb0, voA[0], voA[1], voA[2], voA[3], voA[4], voA[5], voA[6], voA[7], av + 16);
                ld_plane8(sb0 + (8u << 15), voA[0], voA[1], voA[2], voA[3], voA[4], voA[5], voA[6], voA[7], av + 24);
                ld_plane8(sb0, voB[0], voB[1], voB[2], voB[3], voB[4], voB[5], voB[6], voB[7], av + 32);
                ld_plane8(sb0 + (8u << 15), voB[0], voB[1], voB[2], voB[3], voB[4], voB[5], voB[6], voB[7], av + 40);
                if (t > 0) { wait_vm8(av); wait_vm8(av + 8); }
                wait_vm8(av + 16); wait_vm8(av + 24);
                wait_vm8(av + 32); wait_vm8(av + 40);
            } else {
                if (t > 0) {
                    ld_plane8(sb_gh, voA[0], voA[1], voA[2], voA[3], voA[4], voA[5], voA[6], voA[7], av);
                    ld_plane8(sb_gh, voB[0], voB[1], voB[2], voB[3], voB[4], voB[5], voB[6], voB[7], av + 8);
                } else {
#pragma unroll
                    for (int i = 0; i < 16; ++i) av[i] = (intx4){0, 0, 0, 0};
                }
                const uint16_t* eb0 = enc_bf + ((size_t)myrowA << 15) + t * 128 + q * 8;
                const uint16_t* eb1 = eb0 + ((size_t)16 << 15);
#pragma unroll
                for (int kc = 0; kc < 4; ++kc) {
                    __builtin_memcpy(&av[16 + kc], eb0 + kc * 32, 16);
                    __builtin_memcpy(&av[32 + kc], eb1 + kc * 32, 16);
                }
                if (t > 0) { wait_vm8(av); wait_vm8(av + 8); }
            }

            // ---- MFMA: each B-frag read feeds both A-tiles ----
            floatx4 aR[2][2], aZ[2][2], aNi[2][2], aNh[2][2];
#pragma unroll
            for (int mt = 0; mt < 2; ++mt)
#pragma unroll
                for (int sub = 0; sub < 2; ++sub) {
                    floatx4 z = (floatx4){0.f, 0.f, 0.f, 0.f};
                    aR[mt][sub] = z; aZ[mt][sub] = z; aNi[mt][sub] = z; aNh[mt][sub] = z;
                }
            if (l > 0) {
#pragma unroll
                for (int kc = 0; kc < 16; ++kc) {
                    short8 a0 = as_s8(av[16 + kc]);
                    short8 a1 = as_s8(av[32 + kc]);
#pragma unroll
                    for (int sub = 0; sub < 2; ++sub) {
                        short8 b0f = *(const short8*)&sm.g.wgi[wofs_gi[sub][0] + kc * 32];
                        short8 b1f = *(const short8*)&sm.g.wgi[wofs_gi[sub][1] + kc * 32];
                        short8 b2f = *(const short8*)&sm.g.wgi[wofs_gi[sub][2] + kc * 32];
                        aR[0][sub]  = __builtin_amdgcn_mfma_f32_16x16x32_bf16(a0, b0f, aR[0][sub], 0, 0, 0);
                        aR[1][sub]  = __builtin_amdgcn_mfma_f32_16x16x32_bf16(a1, b0f, aR[1][sub], 0, 0, 0);
                        aZ[0][sub]  = __builtin_amdgcn_mfma_f32_16x16x32_bf16(a0, b1f, aZ[0][sub], 0, 0, 0);
                        aZ[1][sub]  = __builtin_amdgcn_mfma_f32_16x16x32_bf16(a1, b1f, aZ[1][sub], 0, 0, 0);
                        aNi[0][sub] = __builtin_amdgcn_mfma_f32_16x16x32_bf16(a0, b2f, aNi[0][sub], 0, 0, 0);
                        aNi[1][sub] = __builtin_amdgcn_mfma_f32_16x16x32_bf16(a1, b2f, aNi[1][sub], 0, 0, 0);
                    }
                }
            } else {
#pragma unroll
                for (int kc = 0; kc < 4; ++kc) {
                    short8 a0 = as_s8(av[16 + kc]);
                    short8 a1 = as_s8(av[32 + kc]);
#pragma unroll
                    for (int sub = 0; sub < 2; ++sub) {
                        short8 b0f = *(const short8*)&sm.g.wgi[wofs_gi[sub][0] + kc * 32];
                        short8 b1f = *(const short8*)&sm.g.wgi[wofs_gi[sub][1] + kc * 32];
                        short8 b2f = *(const short8*)&sm.g.wgi[wofs_gi[sub][2] + kc * 32];
                        aR[0][sub]  = __builtin_amdgcn_mfma_f32_16x16x32_bf16(a0, b0f, aR[0][sub], 0, 0, 0);
                        aR[1][sub]  = __builtin_amdgcn_mfma_f32_16x16x32_bf16(a1, b0f, aR[1][sub], 0, 0, 0);
                        aZ[0][sub]  = __builtin_amdgcn_mfma_f32_16x16x32_bf16(a0, b1f, aZ[0][sub], 0, 0, 0);
                        aZ[1][sub]  = __builtin_amdgcn_mfma_f32_16x16x32_bf16(a1, b1f, aZ[1][sub], 0, 0, 0);
                        aNi[0][sub] = __builtin_amdgcn_mfma_f32_16x16x32_bf16(a0, b2f, aNi[0][sub], 0, 0, 0);
                        aNi[1][sub] = __builtin_amdgcn_mfma_f32_16x16x32_bf16(a1, b2f, aNi[1][sub], 0, 0, 0);
                    }
                }
            }
#pragma unroll
            for (int kc = 0; kc < 8; ++kc) {
                short8 a0 = as_s8(av[kc]);
                short8 a1 = as_s8(av[8 + kc]);
#pragma unroll
                for (int sub = 0; sub < 2; ++sub) {
                    short8 b0f = wghr[sub][0][kc];
                    short8 b1f = wghr[sub][1][kc];
                    short8 b2f = wghr[sub][2][kc];
                    aR[0][sub]  = __builtin_amdgcn_mfma_f32_16x16x32_bf16(a0, b0f, aR[0][sub], 0, 0, 0);
                    aR[1][sub]  = __builtin_amdgcn_mfma_f32_16x16x32_bf16(a1, b0f, aR[1][sub], 0, 0, 0);
                    aZ[0][sub]  = __builtin_amdgcn_mfma_f32_16x16x32_bf16(a0, b1f, aZ[0][sub], 0, 0, 0);
                    aZ[1][sub]  = __builtin_amdgcn_mfma_f32_16x16x32_bf16(a1, b1f, aZ[1][sub], 0, 0, 0);
                    aNh[0][sub] = __builtin_amdgcn_mfma_f32_16x16x32_bf16(a0, b2f, aNh[0][sub], 0, 0, 0);
                    aNh[1][sub] = __builtin_amdgcn_mfma_f32_16x16x32_bf16(a1, b2f, aNh[1][sub], 0, 0, 0);
                }
            }

            // ---- epilogue: gates + state update -> h_out ----
#pragma unroll
            for (int mt = 0; mt < 2; ++mt)
#pragma unroll
                for (int sub = 0; sub < 2; ++sub) {
#pragma unroll
                    for (int r = 0; r < 4; ++r) {
                        float rr = sigmoidf_(aR[mt][sub][r] + bRs[sub]);
                        float zz = sigmoidf_(aZ[mt][sub][r] + bZs[sub]);
                        float nn = tanhf(aNi[mt][sub][r] + bNs[sub] + rr * (aNh[mt][sub][r] + bHNs[sub]));
                        float hn = (1.f - zz) * nn + zz * hreg[mt][sub][r];
                        hreg[mt][sub][r] = hn;
                        sm.g.h_out[(w * 32 + mt * 16 + q * 4 + r) * 32 + sub * 16 + l15] = f2bf(hn);
                    }
                }
            __syncthreads();
            // ---- publish slice: contiguous 8KB burst per block (2 chunks/thr) ----
            {
                int i0 = tid, i1 = tid + 256;
                int r0 = i0 >> 2, p0 = i0 & 3;
                int r1 = i1 >> 2, p1 = i1 & 3;
                uint16_t* base = ring + (size_t)(t & 7) * RSLOT + ((size_t)(sd * 8 + es) << 14);
                uint16_t* d0 = base + (size_t)(row0 + r0) * 32 + p0 * 8;
                uint16_t* d1 = base + (size_t)(row0 + r1) * 32 + p1 * 8;
                st2_coh16_wait(d0, *(const intx4*)&sm.g.h_out[r0 * 32 + p0 * 8],
                               d1, *(const intx4*)&sm.g.h_out[r1 * 32 + p1 * 8]);
            }
            __syncthreads();   // every thread drained its own stores above
            if (tid == 0) {
                __hip_atomic_fetch_add(&produced[PIDX(sd, t, bt)], 1,
                                       __ATOMIC_RELAXED, __HIP_MEMORY_SCOPE_AGENT);
                if (l > 0) {
                    __hip_atomic_fetch_add(&consumed[PIDX(2 * l - 2, t, bt)], 1,
                                           __ATOMIC_RELAXED, __HIP_MEMORY_SCOPE_AGENT);
                    __hip_atomic_fetch_add(&consumed[PIDX(2 * l - 1, t, bt)], 1,
                                           __ATOMIC_RELAXED, __HIP_MEMORY_SCOPE_AGENT);
                }
                if (t >= 1)
                    __hip_atomic_fetch_add(&consumed[PIDX(sd, t - 1, bt)], 1,
                                           __ATOMIC_RELAXED, __HIP_MEMORY_SCOPE_AGENT);
            }
        }
        return;
    }

    // =================== attention block (16 rows, 4 waves) ================
    const int ab = blk - 192;
    const int b0 = ab * 16;
    const int bt = ab >> 3;
    // la tile slots: wave w handles tiles j = w + 4*s (s=0..2) where j<9
    float b1T[3], w2T[3];
#pragma unroll
    for (int s = 0; s < 3; ++s) {
        int j = w + 4 * s;
        if (j < 9) {
            int lA = j / 3, nfA = j % 3;
            b1T[s] = la_b1[lA * 48 + nfA * 16 + l15];
            w2T[s] = la_w2[lA * 48 + nfA * 16 + l15];
        } else { b1T[s] = 0.f; w2T[s] = 0.f; }
    }
    // ---- register-cache loop-invariant MFMA weights (la: 3 tiles, sa: 1) ----
    short8 lawr[3][16];
    short8 sawr[16];
#pragma unroll
    for (int s = 0; s < 3; ++s) {
        int j = w + 4 * s;
        int row = (j < 9) ? ((j / 3) * 48 + (j % 3) * 16 + l15) : 0;  // dummy row if unused
#pragma unroll
        for (int kci = 0; kci < 16; ++kci)
            lawr[s][kci] = *(const short8*)&law1_bf[(size_t)row * 512 + kci * 32 + q * 8];
    }
#pragma unroll
    for (int kci = 0; kci < 16; ++kci)
        sawr[kci] = *(const short8*)&saw1_bf[(size_t)(w * 16 + l15) * 512 + kci * 32 + q * 8];

    float nacc[32];
#pragma unroll
    for (int j = 0; j < 32; ++j) nacc[j] = 0.f;
    float m_r = -1e30f, d_r = 0.f;

    for (int t = 0; t < NT; ++t) {
        if (tid == 0) {
            const int* p4 = &produced[PIDX(4, t, bt)];
            const int* p5 = &produced[PIDX(5, t, bt)];
            while (__hip_atomic_load(p4, __ATOMIC_RELAXED, __HIP_MEMORY_SCOPE_AGENT) < 8)
                __builtin_amdgcn_s_sleep(1);
            while (__hip_atomic_load(p5, __ATOMIC_RELAXED, __HIP_MEMORY_SCOPE_AGENT) < 8)
                __builtin_amdgcn_s_sleep(1);
        }
        __syncthreads();
        // ---- stage all 6 states into hbf (12 chunks/thread) ----
        {
            const uint16_t* base = ring + (size_t)(t & 7) * RSLOT;
            const uint16_t* ps[12];
            int di[12];
#pragma unroll
            for (int i = 0; i < 12; ++i) {
                int f = i * 256 + tid;
                int s = f >> 9, r = (f >> 5) & 15, g = f & 31;
                int esx = g >> 2, c16 = g & 3;
                ps[i] = base + ((size_t)(s * 8 + esx) << 14) + (size_t)(b0 + r) * 32 + c16 * 8;
                di[i] = (s * 16 + r) * 264 + g * 8;
            }
            intx4 v[12];
            ld_sc12(ps[0], ps[1], ps[2], ps[3], ps[4], ps[5],
                    ps[6], ps[7], ps[8], ps[9], ps[10], ps[11], v);
#pragma unroll
            for (int i = 0; i < 12; ++i) *(intx4*)&sm.a.hbf[di[i]] = v[i];
        }
        __syncthreads();
        if (tid == 0) {
#pragma unroll
            for (int s = 0; s < 6; ++s)
                __hip_atomic_fetch_add(&consumed[PIDX(s, t, bt)], 1,
                                       __ATOMIC_RELAXED, __HIP_MEMORY_SCOPE_AGENT);
        }
        // ---- la tiles (up to 3 per wave), weights from registers ----
#pragma unroll
        for (int s = 0; s < 3; ++s) {
            int j = w + 4 * s;
            if (j < 9) {
                int lA = j / 3, nfA = j % 3;
                floatx4 ac = (floatx4){0.f, 0.f, 0.f, 0.f};
#pragma unroll
                for (int kci = 0; kci < 16; ++kci) {
                    int k = kci * 32 + q * 8;
                    int st = 2 * lA + (k >= 256 ? 1 : 0);
                    short8 afr = *(const short8*)&sm.a.hbf[(st * 16 + l15) * 264 + (k & 255)];
                    ac = __builtin_amdgcn_mfma_f32_16x16x32_bf16(afr, lawr[s][kci], ac, 0, 0, 0);
                }
#pragma unroll
                for (int r = 0; r < 4; ++r) {
                    float v = geluf_(ac[r] + b1T[s]) * w2T[s];
                    v += __shfl_xor(v, 1, 64);
                    v += __shfl_xor(v, 2, 64);
                    v += __shfl_xor(v, 4, 64);
                    v += __shfl_xor(v, 8, 64);
                    if (l15 == 0) sm.a.laP[lA][nfA][q * 4 + r] = v;
                }
            }
        }
        // ---- sa tile nf = w (raw pre-acts), weights from registers ----
        {
            floatx4 ac = (floatx4){0.f, 0.f, 0.f, 0.f};
#pragma unroll
            for (int kci = 0; kci < 16; ++kci) {
                int k = kci * 32 + q * 8;
                int st = 4 + (k >= 256 ? 1 : 0);
                short8 afr = *(const short8*)&sm.a.hbf[(st * 16 + l15) * 264 + (k & 255)];
                ac = __builtin_amdgcn_mfma_f32_16x16x32_bf16(afr, sawr[kci], ac, 0, 0, 0);
            }
#pragma unroll
            for (int r = 0; r < 4; ++r) sm.a.saT[w][q * 4 + r][l15] = ac[r];
        }
        __syncthreads();
        // ---- combine: s and logit per row (wave 0) ----
        if (w == 0) {
            int row = l15;
            float sv = 0.f;
#pragma unroll
            for (int l = 0; l < 3; ++l)
                sv += sigmoidf_(sm.a.laP[l][0][row] + sm.a.laP[l][1][row] +
                                sm.a.laP[l][2][row] + la_b2[l]);
            float a2 = 0.f;
#pragma unroll
            for (int i = 0; i < 16; ++i) {
                int c = q * 16 + i;
                float pre = sv * sm.a.saT[q][row][i] + sa_b1[c];
                a2 += pre * sigmoidf_(pre) * sa_w2[c];
            }
            a2 += __shfl_xor(a2, 16, 64);
            a2 += __shfl_xor(a2, 32, 64);
            if (q == 0 && lane < 16) { sm.a.s_s[row] = sv; sm.a.lg_s[row] = a2 + sa_b2[0]; }
        }
        __syncthreads();
        // ---- online softmax update (wave w owns rows 4w..4w+3) ----
        {
            int myrow = 4 * w + (lane >> 4);
            int ci = lane & 15;
            float lg = sm.a.lg_s[myrow], sv = sm.a.s_s[myrow];
            float mn = fmaxf(m_r, lg);
            float cs = expf(m_r - mn);
            float e = expf(lg - mn);
            m_r = mn;
            d_r = d_r * cs + e;
            float wf = e * sv;
            int st = 4 + (ci >> 3);
            int c0 = (ci & 7) * 32;
            const uint16_t* hp = &sm.a.hbf[(size_t)(st * 16 + myrow) * 264 + c0];
            short8 o0 = *(const short8*)hp;
            short8 o1 = *(const short8*)(hp + 8);
            short8 o2 = *(const short8*)(hp + 16);
            short8 o3 = *(const short8*)(hp + 24);
#pragma unroll
            for (int j = 0; j < 8; ++j) {
                nacc[j]      = nacc[j]      * cs + wf * bf2f((uint16_t)o0[j]);
                nacc[8 + j]  = nacc[8 + j]  * cs + wf * bf2f((uint16_t)o1[j]);
                nacc[16 + j] = nacc[16 + j] * cs + wf * bf2f((uint16_t)o2[j]);
                nacc[24 + j] = nacc[24 + j] * cs + wf * bf2f((uint16_t)o3[j]);
            }
        }
        __syncthreads();   // protect hbf/s_s before next step's staging
    }

    // ---- finalize: context -> LN -> FC ----
    {
        int myrow = 4 * w + (lane >> 4);
        int ci = lane & 15;
        float dinv = 1.f / d_r;
        float cv[32];
        float s1 = 0.f, s2 = 0.f;
#pragma unroll
        for (int j = 0; j < 32; ++j) {
            cv[j] = nacc[j] * dinv;
            s1 += cv[j];
            s2 += cv[j] * cv[j];
        }
        s1 += __shfl_xor(s1, 1, 64);  s2 += __shfl_xor(s2, 1, 64);
        s1 += __shfl_xor(s1, 2, 64);  s2 += __shfl_xor(s2, 2, 64);
        s1 += __shfl_xor(s1, 4, 64);  s2 += __shfl_xor(s2, 4, 64);
        s1 += __shfl_xor(s1, 8, 64);  s2 += __shfl_xor(s2, 8, 64);
        float mean = s1 / 512.f;
        float var = s2 / 512.f - mean * mean;
        float rstd = rsqrtf(var + 1e-5f);
        float p0 = 0.f, p1 = 0.f;
#pragma unroll
        for (int j = 0; j < 32; ++j) {
            int g = ci * 32 + j;
            float nv = (cv[j] - mean) * rstd * ln_g[g] + ln_b[g];
            p0 += nv * fc_w[g];
            p1 += nv * fc_w[512 + g];
        }
        p0 += __shfl_xor(p0, 1, 64);  p1 += __shfl_xor(p1, 1, 64);
        p0 += __shfl_xor(p0, 2, 64);  p1 += __shfl_xor(p1, 2, 64);
        p0 += __shfl_xor(p0, 4, 64);  p1 += __shfl_xor(p1, 4, 64);
        p0 += __shfl_xor(p0, 8, 64);  p1 += __shfl_xor(p1, 8, 64);
        if ((lane & 15) == 0) {
            out[(b0 + myrow) * 2 + 0] = p0 + fc_b[0];
            out[(b0 + myrow) * 2 + 1] = p1 + fc_b[1];
        }
    }
}

// ---------------------------------------------------------------------------
extern "C" void kernel_launch(void* const* d_in, const int* in_sizes, int n_in,
                              void* d_out, int out_size, void* d_ws, size_t ws_size,
                              hipStream_t stream) {
    const float* x     = (const float*)d_in[0];
    const float* enc_w = (const float*)d_in[1];
    const float* enc_b = (const float*)d_in[2];
    const float* wih0  = (const float*)d_in[3];
    const float* wihL  = (const float*)d_in[4];
    const float* whh   = (const float*)d_in[5];
    const float* bih   = (const float*)d_in[6];
    const float* bhh   = (const float*)d_in[7];
    const float* la_w1 = (const float*)d_in[8];
    const float* la_b1 = (const float*)d_in[9];
    const float* la_w2 = (const float*)d_in[10];
    const float* la_b2 = (const float*)d_in[11];
    const float* sa_w1 = (const float*)d_in[12];
    const float* sa_b1 = (const float*)d_in[13];
    const float* sa_w2 = (const float*)d_in[14];
    const float* sa_b2 = (const float*)d_in[15];
    const float* ln_g  = (const float*)d_in[16];
    const float* ln_b  = (const float*)d_in[17];
    const float* fc_w  = (const float*)d_in[18];
    const float* fc_b  = (const float*)d_in[19];
    float* out = (float*)d_out;

    uint8_t* wsb = (uint8_t*)d_ws;
    size_t off = 0;
    auto alloc = [&](size_t bytes) -> void* {
        void* p = wsb + off;
        off += (bytes + 255) & ~(size_t)255;
        return p;
    };
    uint16_t* enc_bf  = (uint16_t*)alloc((size_t)NB * 32768 * 2);          // 33.55 MB
    uint16_t* wih0_bf = (uint16_t*)alloc((size_t)2 * NG * 128 * 2);        // 0.39 MB
    uint16_t* wihL_bf = (uint16_t*)alloc((size_t)2 * 2 * NG * 512 * 2);    // 3.15 MB
    uint16_t* whh_bf  = (uint16_t*)alloc((size_t)3 * 2 * NG * 256 * 2);    // 2.36 MB
    uint16_t* law1_bf = (uint16_t*)alloc((size_t)3 * 48 * 512 * 2);        // 0.15 MB
    uint16_t* saw1_bf = (uint16_t*)alloc((size_t)64 * 512 * 2);            // 0.07 MB
    uint16_t* ring    = (uint16_t*)alloc((size_t)R_RING * RSLOT * 2);      // 12.58 MB
    int*      produced= (int*)alloc((size_t)6 * NT * 4 * 4);               // 24 KB
    int*      consumed= (int*)alloc((size_t)6 * NT * 4 * 4);               // 24 KB
    // total ~52.3 MB

    if (ws_size < off) {
        k_sentinel<<<4, 256, 0, stream>>>(out);
        return;
    }

    auto cvt = [&](const float* s, uint16_t* dmem, int n) {
        int n4 = n / 4;
        k_cvt<<<(n4 + 255) / 256, 256, 0, stream>>>(s, dmem, n4);
    };
    cvt(wih0, wih0_bf, 196608);
    cvt(wihL, wihL_bf, 1572864);
    cvt(whh, whh_bf, 1179648);
    cvt(la_w1, law1_bf, 73728);
    cvt(sa_w1, saw1_bf, 32768);
    // zero produced+consumed (contiguous: 2 * 6144 ints = 3072 float4)
    k_zero<<<12, 256, 0, stream>>>((float*)produced, 3072);

    k_encoder<<<dim3(256, 4), 256, 0, stream>>>(x, enc_w, enc_b, enc_bf);

    k_scan<<<224, BTH, 0, stream>>>(enc_bf, wih0_bf, wihL_bf, whh_bf,
                                    bih, bhh, law1_bf, la_b1, la_w2, la_b2,
                                    saw1_bf, sa_b1, sa_w2, sa_b2,
                                    ln_g, ln_b, fc_w, fc_b,
                                    ring, produced, consumed, out);
}

// Round 10
// 3647.412 us; speedup vs baseline: 1.0532x; 1.0532x over previous
//
#include <hip/hip_runtime.h>
#include <stdint.h>

// ---------------------------------------------------------------------------
// GRUClassifier round 17: round-14 base (best verified, 3703us) + wave-
// parallel flag polling. Round-16 post-mortem: (a) r15's NaN was the GRU
// two-phase wait restructure -> wait/load asm cluster is FROZEN at the r14
// structure; (b) attention weight hoist cost ~110us -> reverted (attention
// per-step weight reads were already hidden; GRU stages set the interval).
// This round: the only remaining safe, additive lever on the exposed-latency
// budget — tid0 polled up to 4 agent-coherent flags SERIALLY (~0.25-0.5us
// each cross-L2 round trip) before __syncthreads. Now lane 0 of each wave
// polls one flag concurrently (w0: backpressure, w1: own t-1, w2/w3:
// upstream p0/p1; attention: w0 p4, w1 p5), then the same __syncthreads
// joins. Flag semantics identical; numerics bit-identical.
// Canaries: absmax 0.00390625 exactly; WRITE_SIZE ~4.0e5 KB; conflicts ~4.1e8.
// ---------------------------------------------------------------------------

typedef short short8 __attribute__((ext_vector_type(8)));
typedef float floatx4 __attribute__((ext_vector_type(4)));
typedef int intx4 __attribute__((ext_vector_type(4)));
typedef unsigned long long u64;

#define NB 512
#define NT 256
#define NH 256
#define NG 768
#define R_RING 8
#define RSLOT (6 * NB * NH)          // u16 elems per ring slot
#define BTH 256

__device__ __forceinline__ float bf2f(uint16_t v) {
    uint32_t u = ((uint32_t)v) << 16;
    float f;
    __builtin_memcpy(&f, &u, 4);
    return f;
}
__device__ __forceinline__ uint16_t f2bf(float f) {
    uint32_t u;
    __builtin_memcpy(&u, &f, 4);
    uint32_t r = (u + 0x7FFFu + ((u >> 16) & 1u)) >> 16;
    return (uint16_t)r;
}
__device__ __forceinline__ u64 pack4bf(float4 v) {
    u64 a = f2bf(v.x), b = f2bf(v.y), c = f2bf(v.z), d = f2bf(v.w);
    return a | (b << 16) | (c << 32) | (d << 48);
}
__device__ __forceinline__ float sigmoidf_(float x) { return 1.f / (1.f + expf(-x)); }
__device__ __forceinline__ float geluf_(float x) { return 0.5f * x * (1.f + erff(x * 0.70710678118f)); }
__device__ __forceinline__ short8 as_s8(intx4 v) { short8 r; __builtin_memcpy(&r, &v, 16); return r; }

__device__ __forceinline__ void poll_flag(const int* p, int n) {
    while (__hip_atomic_load(p, __ATOMIC_RELAXED, __HIP_MEMORY_SCOPE_AGENT) < n)
        __builtin_amdgcn_s_sleep(1);
}

// two write-through 16B stores + own-thread drain
__device__ __forceinline__ void st2_coh16_wait(void* p0, intx4 v0, void* p1, intx4 v1) {
    asm volatile("global_store_dwordx4 %0, %1, off sc0 sc1\n\t"
                 "global_store_dwordx4 %2, %3, off sc0 sc1\n\t"
                 "s_waitcnt vmcnt(0)"
                 :: "v"(p0), "v"(v0), "v"(p1), "v"(v1) : "memory");
}

// 8 coherent loads from one plane-base (SGPR) with per-lane 32-bit offsets
__device__ __forceinline__ void ld_plane8(u64 sbase,
    uint32_t o0, uint32_t o1, uint32_t o2, uint32_t o3,
    uint32_t o4, uint32_t o5, uint32_t o6, uint32_t o7, intx4* v) {
    asm volatile(
        "global_load_dwordx4 %0, %8, %16 sc0 sc1\n\t"
        "global_load_dwordx4 %1, %9, %16 sc0 sc1\n\t"
        "global_load_dwordx4 %2, %10, %16 sc0 sc1\n\t"
        "global_load_dwordx4 %3, %11, %16 sc0 sc1\n\t"
        "global_load_dwordx4 %4, %12, %16 sc0 sc1\n\t"
        "global_load_dwordx4 %5, %13, %16 sc0 sc1\n\t"
        "global_load_dwordx4 %6, %14, %16 sc0 sc1\n\t"
        "global_load_dwordx4 %7, %15, %16 sc0 sc1"
        : "=&v"(v[0]), "=&v"(v[1]), "=&v"(v[2]), "=&v"(v[3]),
          "=&v"(v[4]), "=&v"(v[5]), "=&v"(v[6]), "=&v"(v[7])
        : "v"(o0), "v"(o1), "v"(o2), "v"(o3), "v"(o4), "v"(o5), "v"(o6), "v"(o7),
          "s"(sbase)
        : "memory");
}
// drain all outstanding vmem; ties 8 values so their uses can't be hoisted
__device__ __forceinline__ void wait_vm8(intx4* v) {
    asm volatile("s_waitcnt vmcnt(0)"
                 : "+v"(v[0]), "+v"(v[1]), "+v"(v[2]), "+v"(v[3]),
                   "+v"(v[4]), "+v"(v[5]), "+v"(v[6]), "+v"(v[7])
                 :: "memory");
}
// 12 scattered coherent loads (attention staging, 256-thread blocks)
__device__ __forceinline__ void ld_sc12(
    const uint16_t* p0, const uint16_t* p1, const uint16_t* p2,
    const uint16_t* p3, const uint16_t* p4, const uint16_t* p5,
    const uint16_t* p6, const uint16_t* p7, const uint16_t* p8,
    const uint16_t* p9, const uint16_t* p10, const uint16_t* p11, intx4* v) {
    asm volatile(
        "global_load_dwordx4 %0, %12, off sc0 sc1\n\t"
        "global_load_dwordx4 %1, %13, off sc0 sc1\n\t"
        "global_load_dwordx4 %2, %14, off sc0 sc1\n\t"
        "global_load_dwordx4 %3, %15, off sc0 sc1\n\t"
        "global_load_dwordx4 %4, %16, off sc0 sc1\n\t"
        "global_load_dwordx4 %5, %17, off sc0 sc1\n\t"
        "global_load_dwordx4 %6, %18, off sc0 sc1\n\t"
        "global_load_dwordx4 %7, %19, off sc0 sc1\n\t"
        "global_load_dwordx4 %8, %20, off sc0 sc1\n\t"
        "global_load_dwordx4 %9, %21, off sc0 sc1\n\t"
        "global_load_dwordx4 %10, %22, off sc0 sc1\n\t"
        "global_load_dwordx4 %11, %23, off sc0 sc1\n\t"
        "s_waitcnt vmcnt(0)"
        : "=&v"(v[0]), "=&v"(v[1]), "=&v"(v[2]), "=&v"(v[3]),
          "=&v"(v[4]), "=&v"(v[5]), "=&v"(v[6]), "=&v"(v[7]),
          "=&v"(v[8]), "=&v"(v[9]), "=&v"(v[10]), "=&v"(v[11])
        : "v"(p0), "v"(p1), "v"(p2), "v"(p3), "v"(p4), "v"(p5),
          "v"(p6), "v"(p7), "v"(p8), "v"(p9), "v"(p10), "v"(p11)
        : "memory");
}

#define PIDX(s, t, bt) ((((s) * NT) + (t)) * 4 + (bt))

// ---------------- small utility kernels ------------------------------------
__global__ void k_cvt(const float* __restrict__ src, uint16_t* __restrict__ dst, int n4) {
    int i = blockIdx.x * blockDim.x + threadIdx.x;
    if (i < n4) {
        float4 v = ((const float4*)src)[i];
        ushort4 o;
        o.x = f2bf(v.x); o.y = f2bf(v.y); o.z = f2bf(v.z); o.w = f2bf(v.w);
        ((ushort4*)dst)[i] = o;
    }
}
__global__ void k_zero(float* __restrict__ p, int n4) {
    int i = blockIdx.x * blockDim.x + threadIdx.x;
    if (i < n4) ((float4*)p)[i] = make_float4(0.f, 0.f, 0.f, 0.f);
}
__global__ void k_sentinel(float* __restrict__ out) {
    int i = blockIdx.x * blockDim.x + threadIdx.x;
    if (i < 1024) out[i] = -99999.0f;
}

// ---------------- encoder: encoded = mish(x @ enc_w^T + enc_b), bf16 out ----
__global__ __launch_bounds__(256) void k_encoder(
    const float* __restrict__ x, const float* __restrict__ enc_w,
    const float* __restrict__ enc_b, uint16_t* __restrict__ enc_out) {
    const int tid = threadIdx.x;
    const int lane = tid & 63, wid = tid >> 6;
    const int q = lane >> 4, l15 = lane & 15;
    const int wm = wid >> 1, wj = wid & 1;
    const int j0 = blockIdx.x * 128, b0 = blockIdx.y * 128;

    __shared__ uint16_t a_s[128 * 72];
    __shared__ uint16_t w_s[128 * 72];

#pragma unroll
    for (int jj = 0; jj < 8; ++jj) {
        int u = tid + jj * 256;
        int r = u >> 4, c4 = (u & 15) * 4;
        float4 va = *(const float4*)&x[(size_t)(b0 + r) * 64 + c4];
        float4 vw = *(const float4*)&enc_w[(size_t)(j0 + r) * 64 + c4];
        *(u64*)&a_s[r * 72 + c4] = pack4bf(va);
        *(u64*)&w_s[r * 72 + c4] = pack4bf(vw);
    }
    __syncthreads();

    floatx4 acc[4][4];
#pragma unroll
    for (int mi = 0; mi < 4; ++mi)
#pragma unroll
        for (int nf = 0; nf < 4; ++nf) acc[mi][nf] = (floatx4){0.f, 0.f, 0.f, 0.f};

#pragma unroll
    for (int kc = 0; kc < 2; ++kc) {
        short8 af[4], bfg[4];
#pragma unroll
        for (int mi = 0; mi < 4; ++mi)
            af[mi] = *(const short8*)&a_s[(wm * 64 + mi * 16 + l15) * 72 + kc * 32 + q * 8];
#pragma unroll
        for (int nf = 0; nf < 4; ++nf)
            bfg[nf] = *(const short8*)&w_s[(wj * 64 + nf * 16 + l15) * 72 + kc * 32 + q * 8];
#pragma unroll
        for (int mi = 0; mi < 4; ++mi)
#pragma unroll
            for (int nf = 0; nf < 4; ++nf)
                acc[mi][nf] = __builtin_amdgcn_mfma_f32_16x16x32_bf16(af[mi], bfg[nf], acc[mi][nf], 0, 0, 0);
    }

#pragma unroll
    for (int nf = 0; nf < 4; ++nf) {
        int j = j0 + wj * 64 + nf * 16 + l15;
        float eb = enc_b[j];
#pragma unroll
        for (int mi = 0; mi < 4; ++mi)
#pragma unroll
            for (int r = 0; r < 4; ++r) {
                int b = b0 + wm * 64 + mi * 16 + q * 4 + r;
                float v = acc[mi][nf][r] + eb;
                float sp = (v > 20.f) ? v : log1pf(expf(v));
                float m = v * tanhf(sp);
                enc_out[(size_t)b * 32768 + j] = f2bf(m);
            }
    }
}

// ---------------- shared memory layouts ------------------------------------
struct SGru {
    uint16_t wgi[96 * 520];   // [3g*32r][K(+8 pad)]  (row-major, round-9 layout)
    uint16_t h_out[128 * 32]; // publish staging
};
struct SAtt {
    uint16_t hbf[6 * 16 * 264];
    float laP[3][3][16];
    float saT[4][16][17];
    float s_s[16], lg_s[16];
};
union SMem { SGru g; SAtt a; };

// ---------------- pipelined scan kernel ------------------------------------
// grid 224 x 256 thr.
//  b<192: GRU block: sd=b>>5, es=(b&31)>>2 (8 e-slices of 32), bt=b&3.
//         4 waves x 32 rows; gh weights in registers; gi weights in LDS.
//         (load/wait structure byte-identical to verified round 14;
//          flag polls distributed across waves)
//  b>=192: attention block ab=b-192 (32 blocks of 16 rows), 4 waves.
// Ring layout: slot[(t&7)] . plane[sd*8+es] (32KB) . row (64B) . col16.
__global__ __launch_bounds__(BTH, 1) void k_scan(
    const uint16_t* __restrict__ enc_bf,
    const uint16_t* __restrict__ wih0_bf, const uint16_t* __restrict__ wihL_bf,
    const uint16_t* __restrict__ whh_bf,
    const float* __restrict__ bih, const float* __restrict__ bhh,
    const uint16_t* __restrict__ law1_bf, const float* __restrict__ la_b1,
    const float* __restrict__ la_w2, const float* __restrict__ la_b2,
    const uint16_t* __restrict__ saw1_bf, const float* __restrict__ sa_b1,
    const float* __restrict__ sa_w2, const float* __restrict__ sa_b2,
    const float* __restrict__ ln_g, const float* __restrict__ ln_b,
    const float* __restrict__ fc_w, const float* __restrict__ fc_b,
    uint16_t* __restrict__ ring, int* produced, int* consumed,
    float* __restrict__ out) {
    const int blk = blockIdx.x;
    const int tid = threadIdx.x;
    const int w = tid >> 6;          // 0..3
    const int lane = tid & 63;
    const int q = lane >> 4, l15 = lane & 15;

    __shared__ SMem sm;

    if (blk < 192) {
        // =================== GRU stage block (== round 14) =================
        const int sd = blk >> 5;
        const int l = sd >> 1, dd = sd & 1;
        const int rem = blk & 31;
        const int es = rem >> 2;
        const int bt = rem & 3;
        const int row0 = bt * 128;
        const int Kgi = (l == 0) ? 128 : 512;
        const int ksh = (l == 0) ? 7 : 9;
        const int strgi = Kgi + 8;
        const uint16_t* wih = (l == 0) ? wih0_bf + (size_t)dd * NG * 128
                                       : wihL_bf + (size_t)((l - 1) * 2 + dd) * NG * 512;
        const uint16_t* whhp = whh_bf + (size_t)sd * NG * 256;
        const int ncons = (l < 2) ? 32 : 16;

        // ---- load gi weights into LDS (once), row-major round-9 layout ----
        for (int flat = tid * 8; flat < 96 * Kgi; flat += BTH * 8) {
            int r = flat >> ksh, c = flat & (Kgi - 1);
            int g = r >> 5, rr = r & 31;
            int srow = g * 256 + es * 32 + rr;
            *(intx4*)&sm.g.wgi[r * strgi + c] = *(const intx4*)&wih[(size_t)srow * Kgi + c];
        }
        // ---- gh weights: registers, loaded ONCE from global (r13/r14). ----
        short8 wghr[2][3][8];
#pragma unroll
        for (int sub = 0; sub < 2; ++sub)
#pragma unroll
            for (int g = 0; g < 3; ++g)
#pragma unroll
                for (int kc = 0; kc < 8; ++kc)
                    wghr[sub][g][kc] = *(const short8*)&whhp[
                        (size_t)(g * 256 + es * 32 + sub * 16 + l15) * 256 + kc * 32 + q * 8];

        float bRs[2], bZs[2], bNs[2], bHNs[2];
        {
            int ba = sd * NG;
#pragma unroll
            for (int sub = 0; sub < 2; ++sub) {
                int e = es * 32 + sub * 16 + l15;
                bRs[sub] = bih[ba + e] + bhh[ba + e];
                bZs[sub] = bih[ba + 256 + e] + bhh[ba + 256 + e];
                bNs[sub] = bih[ba + 512 + e];
                bHNs[sub] = bhh[ba + 512 + e];
            }
        }
        int wofs_gi[2][3];
#pragma unroll
        for (int sub = 0; sub < 2; ++sub)
#pragma unroll
            for (int g = 0; g < 3; ++g)
                wofs_gi[sub][g] = (g * 32 + sub * 16 + l15) * strgi + q * 8;
        // fp32 hidden carry: hreg[mt][sub][r], rows w*32 + mt*16 + q*4 + r
        float hreg[2][2][4];
#pragma unroll
        for (int mt = 0; mt < 2; ++mt)
#pragma unroll
            for (int sub = 0; sub < 2; ++sub)
#pragma unroll
                for (int r = 0; r < 4; ++r) hreg[mt][sub][r] = 0.f;

        const int myrowA = row0 + w * 32 + l15;     // A-tile 0 row; tile 1 = +16
        // loop-invariant per-lane plane offsets (bytes): kc*32KB + row*64 + q*16
        uint32_t voA[8], voB[8];
#pragma unroll
        for (int kc = 0; kc < 8; ++kc) {
            voA[kc] = (uint32_t)(kc * 32768 + myrowA * 64 + q * 16);
            voB[kc] = voA[kc] + 1024;               // +16 rows
        }
        const u64 ring_u = (u64)(uintptr_t)ring;
        __syncthreads();

        for (int t = 0; t < NT; ++t) {
            // ---- waits: distributed across waves (lane 0 of each wave) ----
            // w0: ring backpressure; w1: own stage t-1; w2/w3: upstream t.
            if (tid == 0) {
                if (t >= R_RING) poll_flag(&consumed[PIDX(sd, t - R_RING, bt)], ncons);
            } else if (tid == 64) {
                if (t >= 1) poll_flag(&produced[PIDX(sd, t - 1, bt)], 8);
            } else if (tid == 128) {
                if (l > 0) poll_flag(&produced[PIDX(2 * (l - 1), t, bt)], 8);
            } else if (tid == 192) {
                if (l > 0) poll_flag(&produced[PIDX(2 * (l - 1) + 1, t, bt)], 8);
            }
            __syncthreads();

            // ---- A-fragment loads (all STATIC av indices -> registers) ----
            // av[0..7]=gh mt0, av[8..15]=gh mt1,
            // av[16..31]=gi mt0, av[32..47]=gi mt1
            intx4 av[48];
            const u64 sb_gh = ring_u + (u64)((t - 1) & 7) * (RSLOT * 2) + ((u64)(sd * 8) << 15);
            if (l > 0) {
                const u64 sb0 = ring_u + (u64)(t & 7) * (RSLOT * 2) + ((u64)((2 * l - 2) * 8) << 15);
                if (t > 0) {
                    ld_plane8(sb_gh, voA[0], voA[1], voA[2], voA[3], voA[4], voA[5], voA[6], voA[7], av);
                    ld_plane8(sb_gh, voB[0], voB[1], voB[2], voB[3], voB[4], voB[5], voB[6], voB[7], av + 8);
                } else {
#pragma unroll
                    for (int i = 0; i < 16; ++i) av[i] = (intx4){0, 0, 0, 0};
                }
                ld_plane8(sb0, voA[0], voA[1], voA[2], voA[3], voA[4], voA[5], voA[6], voA[7], av + 16);
                ld_plane8(sb0 + (8u << 15), voA[0], voA[1], voA[2], voA[3], voA[4], voA[5], voA[6], voA[7], av + 24);
                ld_plane8(sb0, voB[0], voB[1], voB[2], voB[3], voB[4], voB[5], voB[6], voB[7], av + 32);
                ld_plane8(sb0 + (8u << 15), voB[0], voB[1], voB[2], voB[3], voB[4], voB[5], voB[6], voB[7], av + 40);
                if (t > 0) { wait_vm8(av); wait_vm8(av + 8); }
                wait_vm8(av + 16); wait_vm8(av + 24);
                wait_vm8(av + 32); wait_vm8(av + 40);
            } else {
                if (t > 0) {
                    ld_plane8(sb_gh, voA[0], voA[1], voA[2], voA[3], voA[4], voA[5], voA[6], voA[7], av);
                    ld_plane8(sb_gh, voB[0], voB[1], voB[2], voB[3], voB[4], voB[5], voB[6], voB[7], av + 8);
                } else {
#pragma unroll
                    for (int i = 0; i < 16; ++i) av[i] = (intx4){0, 0, 0, 0};
                }
                const uint16_t* eb0 = enc_bf + ((size_t)myrowA << 15) + t * 128 + q * 8;
                const uint16_t* eb1 = eb0 + ((size_t)16 << 15);
#pragma unroll
                for (int kc = 0; kc < 4; ++kc) {
                    __builtin_memcpy(&av[16 + kc], eb0 + kc * 32, 16);
                    __builtin_memcpy(&av[32 + kc], eb1 + kc * 32, 16);
                }
                if (t > 0) { wait_vm8(av); wait_vm8(av + 8); }
            }

            // ---- MFMA: each B-frag read feeds both A-tiles ----
            floatx4 aR[2][2], aZ[2][2], aNi[2][2], aNh[2][2];
#pragma unroll
            for (int mt = 0; mt < 2; ++mt)
#pragma unroll
                for (int sub = 0; sub < 2; ++sub) {
                    floatx4 z = (floatx4){0.f, 0.f, 0.f, 0.f};
                    aR[mt][sub] = z; aZ[mt][sub] = z; aNi[mt][sub] = z; aNh[mt][sub] = z;
                }
            if (l > 0) {
#pragma unroll
                for (int kc = 0; kc < 16; ++kc) {
                    short8 a0 = as_s8(av[16 + kc]);
                    short8 a1 = as_s8(av[32 + kc]);
#pragma unroll
                    for (int sub = 0; sub < 2; ++sub) {
                        short8 b0f = *(const short8*)&sm.g.wgi[wofs_gi[sub][0] + kc * 32];
                        short8 b1f = *(const short8*)&sm.g.wgi[wofs_gi[sub][1] + kc * 32];
                        short8 b2f = *(const short8*)&sm.g.wgi[wofs_gi[sub][2] + kc * 32];
                        aR[0][sub]  = __builtin_amdgcn_mfma_f32_16x16x32_bf16(a0, b0f, aR[0][sub], 0, 0, 0);
                        aR[1][sub]  = __builtin_amdgcn_mfma_f32_16x16x32_bf16(a1, b0f, aR[1][sub], 0, 0, 0);
                        aZ[0][sub]  = __builtin_amdgcn_mfma_f32_16x16x32_bf16(a0, b1f, aZ[0][sub], 0, 0, 0);
                        aZ[1][sub]  = __builtin_amdgcn_mfma_f32_16x16x32_bf16(a1, b1f, aZ[1][sub], 0, 0, 0);
                        aNi[0][sub] = __builtin_amdgcn_mfma_f32_16x16x32_bf16(a0, b2f, aNi[0][sub], 0, 0, 0);
                        aNi[1][sub] = __builtin_amdgcn_mfma_f32_16x16x32_bf16(a1, b2f, aNi[1][sub], 0, 0, 0);
                    }
                }
            } else {
#pragma unroll
                for (int kc = 0; kc < 4; ++kc) {
                    short8 a0 = as_s8(av[16 + kc]);
                    short8 a1 = as_s8(av[32 + kc]);
#pragma unroll
                    for (int sub = 0; sub < 2; ++sub) {
                        short8 b0f = *(const short8*)&sm.g.wgi[wofs_gi[sub][0] + kc * 32];
                        short8 b1f = *(const short8*)&sm.g.wgi[wofs_gi[sub][1] + kc * 32];
                        short8 b2f = *(const short8*)&sm.g.wgi[wofs_gi[sub][2] + kc * 32];
                        aR[0][sub]  = __builtin_amdgcn_mfma_f32_16x16x32_bf16(a0, b0f, aR[0][sub], 0, 0, 0);
                        aR[1][sub]  = __builtin_amdgcn_mfma_f32_16x16x32_bf16(a1, b0f, aR[1][sub], 0, 0, 0);
                        aZ[0][sub]  = __builtin_amdgcn_mfma_f32_16x16x32_bf16(a0, b1f, aZ[0][sub], 0, 0, 0);
                        aZ[1][sub]  = __builtin_amdgcn_mfma_f32_16x16x32_bf16(a1, b1f, aZ[1][sub], 0, 0, 0);
                        aNi[0][sub] = __builtin_amdgcn_mfma_f32_16x16x32_bf16(a0, b2f, aNi[0][sub], 0, 0, 0);
                        aNi[1][sub] = __builtin_amdgcn_mfma_f32_16x16x32_bf16(a1, b2f, aNi[1][sub], 0, 0, 0);
                    }
                }
            }
#pragma unroll
            for (int kc = 0; kc < 8; ++kc) {
                short8 a0 = as_s8(av[kc]);
                short8 a1 = as_s8(av[8 + kc]);
#pragma unroll
                for (int sub = 0; sub < 2; ++sub) {
                    short8 b0f = wghr[sub][0][kc];
                    short8 b1f = wghr[sub][1][kc];
                    short8 b2f = wghr[sub][2][kc];
                    aR[0][sub]  = __builtin_amdgcn_mfma_f32_16x16x32_bf16(a0, b0f, aR[0][sub], 0, 0, 0);
                    aR[1][sub]  = __builtin_amdgcn_mfma_f32_16x16x32_bf16(a1, b0f, aR[1][sub], 0, 0, 0);
                    aZ[0][sub]  = __builtin_amdgcn_mfma_f32_16x16x32_bf16(a0, b1f, aZ[0][sub], 0, 0, 0);
                    aZ[1][sub]  = __builtin_amdgcn_mfma_f32_16x16x32_bf16(a1, b1f, aZ[1][sub], 0, 0, 0);
                    aNh[0][sub] = __builtin_amdgcn_mfma_f32_16x16x32_bf16(a0, b2f, aNh[0][sub], 0, 0, 0);
                    aNh[1][sub] = __builtin_amdgcn_mfma_f32_16x16x32_bf16(a1, b2f, aNh[1][sub], 0, 0, 0);
                }
            }

            // ---- epilogue: gates + state update -> h_out ----
#pragma unroll
            for (int mt = 0; mt < 2; ++mt)
#pragma unroll
                for (int sub = 0; sub < 2; ++sub) {
#pragma unroll
                    for (int r = 0; r < 4; ++r) {
                        float rr = sigmoidf_(aR[mt][sub][r] + bRs[sub]);
                        float zz = sigmoidf_(aZ[mt][sub][r] + bZs[sub]);
                        float nn = tanhf(aNi[mt][sub][r] + bNs[sub] + rr * (aNh[mt][sub][r] + bHNs[sub]));
                        float hn = (1.f - zz) * nn + zz * hreg[mt][sub][r];
                        hreg[mt][sub][r] = hn;
                        sm.g.h_out[(w * 32 + mt * 16 + q * 4 + r) * 32 + sub * 16 + l15] = f2bf(hn);
                    }
                }
            __syncthreads();
            // ---- publish slice: contiguous 8KB burst per block (2 chunks/thr) ----
            {
                int i0 = tid, i1 = tid + 256;
                int r0 = i0 >> 2, p0 = i0 & 3;
                int r1 = i1 >> 2, p1 = i1 & 3;
                uint16_t* base = ring + (size_t)(t & 7) * RSLOT + ((size_t)(sd * 8 + es) << 14);
                uint16_t* d0 = base + (size_t)(row0 + r0) * 32 + p0 * 8;
                uint16_t* d1 = base + (size_t)(row0 + r1) * 32 + p1 * 8;
                st2_coh16_wait(d0, *(const intx4*)&sm.g.h_out[r0 * 32 + p0 * 8],
                               d1, *(const intx4*)&sm.g.h_out[r1 * 32 + p1 * 8]);
            }
            __syncthreads();   // every thread drained its own stores above
            if (tid == 0) {
                __hip_atomic_fetch_add(&produced[PIDX(sd, t, bt)], 1,
                                       __ATOMIC_RELAXED, __HIP_MEMORY_SCOPE_AGENT);
                if (l > 0) {
                    __hip_atomic_fetch_add(&consumed[PIDX(2 * l - 2, t, bt)], 1,
                                           __ATOMIC_RELAXED, __HIP_MEMORY_SCOPE_AGENT);
                    __hip_atomic_fetch_add(&consumed[PIDX(2 * l - 1, t, bt)], 1,
                                           __ATOMIC_RELAXED, __HIP_MEMORY_SCOPE_AGENT);
                }
                if (t >= 1)
                    __hip_atomic_fetch_add(&consumed[PIDX(sd, t - 1, bt)], 1,
                                           __ATOMIC_RELAXED, __HIP_MEMORY_SCOPE_AGENT);
            }
        }
        return;
    }

    // =================== attention block (16 rows, 4 waves) ================
    const int ab = blk - 192;
    const int b0 = ab * 16;
    const int bt = ab >> 3;
    // la tile slots: wave w handles tiles j = w + 4*s (s=0..2) where j<9
    float b1T[3], w2T[3];
#pragma unroll
    for (int s = 0; s < 3; ++s) {
        int j = w + 4 * s;
        if (j < 9) {
            int lA = j / 3, nfA = j % 3;
            b1T[s] = la_b1[lA * 48 + nfA * 16 + l15];
            w2T[s] = la_w2[lA * 48 + nfA * 16 + l15];
        } else { b1T[s] = 0.f; w2T[s] = 0.f; }
    }
    float nacc[32];
#pragma unroll
    for (int j = 0; j < 32; ++j) nacc[j] = 0.f;
    float m_r = -1e30f, d_r = 0.f;

    for (int t = 0; t < NT; ++t) {
        // ---- waits: distributed (w0 polls p4, w1 polls p5) ----
        if (tid == 0) {
            poll_flag(&produced[PIDX(4, t, bt)], 8);
        } else if (tid == 64) {
            poll_flag(&produced[PIDX(5, t, bt)], 8);
        }
        __syncthreads();
        // ---- stage all 6 states into hbf (12 chunks/thread) ----
        {
            const uint16_t* base = ring + (size_t)(t & 7) * RSLOT;
            const uint16_t* ps[12];
            int di[12];
#pragma unroll
            for (int i = 0; i < 12; ++i) {
                int f = i * 256 + tid;
                int s = f >> 9, r = (f >> 5) & 15, g = f & 31;
                int esx = g >> 2, c16 = g & 3;
                ps[i] = base + ((size_t)(s * 8 + esx) << 14) + (size_t)(b0 + r) * 32 + c16 * 8;
                di[i] = (s * 16 + r) * 264 + g * 8;
            }
            intx4 v[12];
            ld_sc12(ps[0], ps[1], ps[2], ps[3], ps[4], ps[5],
                    ps[6], ps[7], ps[8], ps[9], ps[10], ps[11], v);
#pragma unroll
            for (int i = 0; i < 12; ++i) *(intx4*)&sm.a.hbf[di[i]] = v[i];
        }
        __syncthreads();
        if (tid == 0) {
#pragma unroll
            for (int s = 0; s < 6; ++s)
                __hip_atomic_fetch_add(&consumed[PIDX(s, t, bt)], 1,
                                       __ATOMIC_RELAXED, __HIP_MEMORY_SCOPE_AGENT);
        }
        // ---- la tiles (up to 3 per wave) ----
#pragma unroll
        for (int s = 0; s < 3; ++s) {
            int j = w + 4 * s;
            if (j < 9) {
                int lA = j / 3, nfA = j % 3;
                floatx4 ac = (floatx4){0.f, 0.f, 0.f, 0.f};
#pragma unroll 2
                for (int kc = 0; kc < 512; kc += 32) {
                    int k = kc + q * 8;
                    int st = 2 * lA + (k >= 256 ? 1 : 0);
                    short8 afr = *(const short8*)&sm.a.hbf[(st * 16 + l15) * 264 + (k & 255)];
                    const uint16_t* wr = law1_bf + (size_t)(lA * 48 + nfA * 16 + l15) * 512 + k;
                    ac = __builtin_amdgcn_mfma_f32_16x16x32_bf16(afr, *(const short8*)wr, ac, 0, 0, 0);
                }
#pragma unroll
                for (int r = 0; r < 4; ++r) {
                    float v = geluf_(ac[r] + b1T[s]) * w2T[s];
                    v += __shfl_xor(v, 1, 64);
                    v += __shfl_xor(v, 2, 64);
                    v += __shfl_xor(v, 4, 64);
                    v += __shfl_xor(v, 8, 64);
                    if (l15 == 0) sm.a.laP[lA][nfA][q * 4 + r] = v;
                }
            }
        }
        // ---- sa tile nf = w (raw pre-acts) ----
        {
            floatx4 ac = (floatx4){0.f, 0.f, 0.f, 0.f};
#pragma unroll 2
            for (int kc = 0; kc < 512; kc += 32) {
                int k = kc + q * 8;
                int st = 4 + (k >= 256 ? 1 : 0);
                short8 afr = *(const short8*)&sm.a.hbf[(st * 16 + l15) * 264 + (k & 255)];
                const uint16_t* wr = saw1_bf + (size_t)(w * 16 + l15) * 512 + k;
                ac = __builtin_amdgcn_mfma_f32_16x16x32_bf16(afr, *(const short8*)wr, ac, 0, 0, 0);
            }
#pragma unroll
            for (int r = 0; r < 4; ++r) sm.a.saT[w][q * 4 + r][l15] = ac[r];
        }
        __syncthreads();
        // ---- combine: s and logit per row (wave 0) ----
        if (w == 0) {
            int row = l15;
            float sv = 0.f;
#pragma unroll
            for (int l = 0; l < 3; ++l)
                sv += sigmoidf_(sm.a.laP[l][0][row] + sm.a.laP[l][1][row] +
                                sm.a.laP[l][2][row] + la_b2[l]);
            float a2 = 0.f;
#pragma unroll
            for (int i = 0; i < 16; ++i) {
                int c = q * 16 + i;
                float pre = sv * sm.a.saT[q][row][i] + sa_b1[c];
                a2 += pre * sigmoidf_(pre) * sa_w2[c];
            }
            a2 += __shfl_xor(a2, 16, 64);
            a2 += __shfl_xor(a2, 32, 64);
            if (q == 0 && lane < 16) { sm.a.s_s[row] = sv; sm.a.lg_s[row] = a2 + sa_b2[0]; }
        }
        __syncthreads();
        // ---- online softmax update (wave w owns rows 4w..4w+3) ----
        {
            int myrow = 4 * w + (lane >> 4);
            int ci = lane & 15;
            float lg = sm.a.lg_s[myrow], sv = sm.a.s_s[myrow];
            float mn = fmaxf(m_r, lg);
            float cs = expf(m_r - mn);
            float e = expf(lg - mn);
            m_r = mn;
            d_r = d_r * cs + e;
            float wf = e * sv;
            int st = 4 + (ci >> 3);
            int c0 = (ci & 7) * 32;
            const uint16_t* hp = &sm.a.hbf[(size_t)(st * 16 + myrow) * 264 + c0];
            short8 o0 = *(const short8*)hp;
            short8 o1 = *(const short8*)(hp + 8);
            short8 o2 = *(const short8*)(hp + 16);
            short8 o3 = *(const short8*)(hp + 24);
#pragma unroll
            for (int j = 0; j < 8; ++j) {
                nacc[j]      = nacc[j]      * cs + wf * bf2f((uint16_t)o0[j]);
                nacc[8 + j]  = nacc[8 + j]  * cs + wf * bf2f((uint16_t)o1[j]);
                nacc[16 + j] = nacc[16 + j] * cs + wf * bf2f((uint16_t)o2[j]);
                nacc[24 + j] = nacc[24 + j] * cs + wf * bf2f((uint16_t)o3[j]);
            }
        }
        __syncthreads();   // protect hbf/s_s before next step's staging
    }

    // ---- finalize: context -> LN -> FC ----
    {
        int myrow = 4 * w + (lane >> 4);
        int ci = lane & 15;
        float dinv = 1.f / d_r;
        float cv[32];
        float s1 = 0.f, s2 = 0.f;
#pragma unroll
        for (int j = 0; j < 32; ++j) {
            cv[j] = nacc[j] * dinv;
            s1 += cv[j];
            s2 += cv[j] * cv[j];
        }
        s1 += __shfl_xor(s1, 1, 64);  s2 += __shfl_xor(s2, 1, 64);
        s1 += __shfl_xor(s1, 2, 64);  s2 += __shfl_xor(s2, 2, 64);
        s1 += __shfl_xor(s1, 4, 64);  s2 += __shfl_xor(s2, 4, 64);
        s1 += __shfl_xor(s1, 8, 64);  s2 += __shfl_xor(s2, 8, 64);
        float mean = s1 / 512.f;
        float var = s2 / 512.f - mean * mean;
        float rstd = rsqrtf(var + 1e-5f);
        float p0 = 0.f, p1 = 0.f;
#pragma unroll
        for (int j = 0; j < 32; ++j) {
            int g = ci * 32 + j;
            float nv = (cv[j] - mean) * rstd * ln_g[g] + ln_b[g];
            p0 += nv * fc_w[g];
            p1 += nv * fc_w[512 + g];
        }
        p0 += __shfl_xor(p0, 1, 64);  p1 += __shfl_xor(p1, 1, 64);
        p0 += __shfl_xor(p0, 2, 64);  p1 += __shfl_xor(p1, 2, 64);
        p0 += __shfl_xor(p0, 4, 64);  p1 += __shfl_xor(p1, 4, 64);
        p0 += __shfl_xor(p0, 8, 64);  p1 += __shfl_xor(p1, 8, 64);
        if ((lane & 15) == 0) {
            out[(b0 + myrow) * 2 + 0] = p0 + fc_b[0];
            out[(b0 + myrow) * 2 + 1] = p1 + fc_b[1];
        }
    }
}

// ---------------------------------------------------------------------------
extern "C" void kernel_launch(void* const* d_in, const int* in_sizes, int n_in,
                              void* d_out, int out_size, void* d_ws, size_t ws_size,
                              hipStream_t stream) {
    const float* x     = (const float*)d_in[0];
    const float* enc_w = (const float*)d_in[1];
    const float* enc_b = (const float*)d_in[2];
    const float* wih0  = (const float*)d_in[3];
    const float* wihL  = (const float*)d_in[4];
    const float* whh   = (const float*)d_in[5];
    const float* bih   = (const float*)d_in[6];
    const float* bhh   = (const float*)d_in[7];
    const float* la_w1 = (const float*)d_in[8];
    const float* la_b1 = (const float*)d_in[9];
    const float* la_w2 = (const float*)d_in[10];
    const float* la_b2 = (const float*)d_in[11];
    const float* sa_w1 = (const float*)d_in[12];
    const float* sa_b1 = (const float*)d_in[13];
    const float* sa_w2 = (const float*)d_in[14];
    const float* sa_b2 = (const float*)d_in[15];
    const float* ln_g  = (const float*)d_in[16];
    const float* ln_b  = (const float*)d_in[17];
    const float* fc_w  = (const float*)d_in[18];
    const float* fc_b  = (const float*)d_in[19];
    float* out = (float*)d_out;

    uint8_t* wsb = (uint8_t*)d_ws;
    size_t off = 0;
    auto alloc = [&](size_t bytes) -> void* {
        void* p = wsb + off;
        off += (bytes + 255) & ~(size_t)255;
        return p;
    };
    uint16_t* enc_bf  = (uint16_t*)alloc((size_t)NB * 32768 * 2);          // 33.55 MB
    uint16_t* wih0_bf = (uint16_t*)alloc((size_t)2 * NG * 128 * 2);        // 0.39 MB
    uint16_t* wihL_bf = (uint16_t*)alloc((size_t)2 * 2 * NG * 512 * 2);    // 3.15 MB
    uint16_t* whh_bf  = (uint16_t*)alloc((size_t)3 * 2 * NG * 256 * 2);    // 2.36 MB
    uint16_t* law1_bf = (uint16_t*)alloc((size_t)3 * 48 * 512 * 2);        // 0.15 MB
    uint16_t* saw1_bf = (uint16_t*)alloc((size_t)64 * 512 * 2);            // 0.07 MB
    uint16_t* ring    = (uint16_t*)alloc((size_t)R_RING * RSLOT * 2);      // 12.58 MB
    int*      produced= (int*)alloc((size_t)6 * NT * 4 * 4);               // 24 KB
    int*      consumed= (int*)alloc((size_t)6 * NT * 4 * 4);               // 24 KB
    // total ~52.3 MB

    if (ws_size < off) {
        k_sentinel<<<4, 256, 0, stream>>>(out);
        return;
    }

    auto cvt = [&](const float* s, uint16_t* dmem, int n) {
        int n4 = n / 4;
        k_cvt<<<(n4 + 255) / 256, 256, 0, stream>>>(s, dmem, n4);
    };
    cvt(wih0, wih0_bf, 196608);
    cvt(wihL, wihL_bf, 1572864);
    cvt(whh, whh_bf, 1179648);
    cvt(la_w1, law1_bf, 73728);
    cvt(sa_w1, saw1_bf, 32768);
    // zero produced+consumed (contiguous: 2 * 6144 ints = 3072 float4)
    k_zero<<<12, 256, 0, stream>>>((float*)produced, 3072);

    k_encoder<<<dim3(256, 4), 256, 0, stream>>>(x, enc_w, enc_b, enc_bf);

    k_scan<<<224, BTH, 0, stream>>>(enc_bf, wih0_bf, wihL_bf, whh_bf,
                                    bih, bhh, law1_bf, la_b1, la_w2, la_b2,
                                    saw1_bf, sa_b1, sa_w2, sa_b2,
                                    ln_g, ln_b, fc_w, fc_b,
                                    ring, produced, consumed, out);
}

// Round 11
// 3593.613 us; speedup vs baseline: 1.0690x; 1.0150x over previous
//
#include <hip/hip_runtime.h>
#include <stdint.h>

// ---------------------------------------------------------------------------
// GRUClassifier round 18: r17 base (3647us) + odd-stride wgi + b64 fragment
// reads (bank-conflict fix that does NOT touch the cursed surfaces).
// Evidence: SQ_LDS_BANK_CONFLICT scales exactly with B-fragment LDS reads
// (1.2e9@144 -> 6.3e8@72 -> 4.07e8@48 reads/wave-step) => counter ~= wgi
// reads. b128 reads force start-bank = 0 mod 4 (8 starts, 8-way, 2.94x).
// Fix: stride 520 -> 524 u16 (1048B = 8 mod 16, 0 mod 8) and read each
// fragment as TWO b64s: start bank = (l15*6 + q*4 + half*2) mod 32 ->
// 16 distinct starts, ~4 lanes each (near-free). Same (r,c) mapping, same
// staging loop (two u64 stores), same global addresses, same MFMA order ->
// bit-identical numerics. Register caching is closed (VGPR budget ~490/512).
// Canaries: absmax 0.00390625 exactly; WRITE_SIZE ~4.0e5; conflicts ~1.5e8.
// ---------------------------------------------------------------------------

typedef short short8 __attribute__((ext_vector_type(8)));
typedef float floatx4 __attribute__((ext_vector_type(4)));
typedef int intx4 __attribute__((ext_vector_type(4)));
typedef unsigned long long u64;

#define NB 512
#define NT 256
#define NH 256
#define NG 768
#define R_RING 8
#define RSLOT (6 * NB * NH)          // u16 elems per ring slot
#define BTH 256

__device__ __forceinline__ float bf2f(uint16_t v) {
    uint32_t u = ((uint32_t)v) << 16;
    float f;
    __builtin_memcpy(&f, &u, 4);
    return f;
}
__device__ __forceinline__ uint16_t f2bf(float f) {
    uint32_t u;
    __builtin_memcpy(&u, &f, 4);
    uint32_t r = (u + 0x7FFFu + ((u >> 16) & 1u)) >> 16;
    return (uint16_t)r;
}
__device__ __forceinline__ u64 pack4bf(float4 v) {
    u64 a = f2bf(v.x), b = f2bf(v.y), c = f2bf(v.z), d = f2bf(v.w);
    return a | (b << 16) | (c << 32) | (d << 48);
}
__device__ __forceinline__ float sigmoidf_(float x) { return 1.f / (1.f + expf(-x)); }
__device__ __forceinline__ float geluf_(float x) { return 0.5f * x * (1.f + erff(x * 0.70710678118f)); }
__device__ __forceinline__ short8 as_s8(intx4 v) { short8 r; __builtin_memcpy(&r, &v, 16); return r; }

// assemble a short8 B-fragment from two 8B LDS reads (8B-aligned rows)
__device__ __forceinline__ short8 lds_frag(const uint16_t* p) {
    u64 lo = *(const u64*)p;
    u64 hi = *(const u64*)(p + 4);
    short8 r;
    __builtin_memcpy(&r, &lo, 8);
    __builtin_memcpy((char*)&r + 8, &hi, 8);
    return r;
}

__device__ __forceinline__ void poll_flag(const int* p, int n) {
    while (__hip_atomic_load(p, __ATOMIC_RELAXED, __HIP_MEMORY_SCOPE_AGENT) < n)
        __builtin_amdgcn_s_sleep(1);
}

// two write-through 16B stores + own-thread drain
__device__ __forceinline__ void st2_coh16_wait(void* p0, intx4 v0, void* p1, intx4 v1) {
    asm volatile("global_store_dwordx4 %0, %1, off sc0 sc1\n\t"
                 "global_store_dwordx4 %2, %3, off sc0 sc1\n\t"
                 "s_waitcnt vmcnt(0)"
                 :: "v"(p0), "v"(v0), "v"(p1), "v"(v1) : "memory");
}

// 8 coherent loads from one plane-base (SGPR) with per-lane 32-bit offsets
__device__ __forceinline__ void ld_plane8(u64 sbase,
    uint32_t o0, uint32_t o1, uint32_t o2, uint32_t o3,
    uint32_t o4, uint32_t o5, uint32_t o6, uint32_t o7, intx4* v) {
    asm volatile(
        "global_load_dwordx4 %0, %8, %16 sc0 sc1\n\t"
        "global_load_dwordx4 %1, %9, %16 sc0 sc1\n\t"
        "global_load_dwordx4 %2, %10, %16 sc0 sc1\n\t"
        "global_load_dwordx4 %3, %11, %16 sc0 sc1\n\t"
        "global_load_dwordx4 %4, %12, %16 sc0 sc1\n\t"
        "global_load_dwordx4 %5, %13, %16 sc0 sc1\n\t"
        "global_load_dwordx4 %6, %14, %16 sc0 sc1\n\t"
        "global_load_dwordx4 %7, %15, %16 sc0 sc1"
        : "=&v"(v[0]), "=&v"(v[1]), "=&v"(v[2]), "=&v"(v[3]),
          "=&v"(v[4]), "=&v"(v[5]), "=&v"(v[6]), "=&v"(v[7])
        : "v"(o0), "v"(o1), "v"(o2), "v"(o3), "v"(o4), "v"(o5), "v"(o6), "v"(o7),
          "s"(sbase)
        : "memory");
}
// drain all outstanding vmem; ties 8 values so their uses can't be hoisted
__device__ __forceinline__ void wait_vm8(intx4* v) {
    asm volatile("s_waitcnt vmcnt(0)"
                 : "+v"(v[0]), "+v"(v[1]), "+v"(v[2]), "+v"(v[3]),
                   "+v"(v[4]), "+v"(v[5]), "+v"(v[6]), "+v"(v[7])
                 :: "memory");
}
// 12 scattered coherent loads (attention staging, 256-thread blocks)
__device__ __forceinline__ void ld_sc12(
    const uint16_t* p0, const uint16_t* p1, const uint16_t* p2,
    const uint16_t* p3, const uint16_t* p4, const uint16_t* p5,
    const uint16_t* p6, const uint16_t* p7, const uint16_t* p8,
    const uint16_t* p9, const uint16_t* p10, const uint16_t* p11, intx4* v) {
    asm volatile(
        "global_load_dwordx4 %0, %12, off sc0 sc1\n\t"
        "global_load_dwordx4 %1, %13, off sc0 sc1\n\t"
        "global_load_dwordx4 %2, %14, off sc0 sc1\n\t"
        "global_load_dwordx4 %3, %15, off sc0 sc1\n\t"
        "global_load_dwordx4 %4, %16, off sc0 sc1\n\t"
        "global_load_dwordx4 %5, %17, off sc0 sc1\n\t"
        "global_load_dwordx4 %6, %18, off sc0 sc1\n\t"
        "global_load_dwordx4 %7, %19, off sc0 sc1\n\t"
        "global_load_dwordx4 %8, %20, off sc0 sc1\n\t"
        "global_load_dwordx4 %9, %21, off sc0 sc1\n\t"
        "global_load_dwordx4 %10, %22, off sc0 sc1\n\t"
        "global_load_dwordx4 %11, %23, off sc0 sc1\n\t"
        "s_waitcnt vmcnt(0)"
        : "=&v"(v[0]), "=&v"(v[1]), "=&v"(v[2]), "=&v"(v[3]),
          "=&v"(v[4]), "=&v"(v[5]), "=&v"(v[6]), "=&v"(v[7]),
          "=&v"(v[8]), "=&v"(v[9]), "=&v"(v[10]), "=&v"(v[11])
        : "v"(p0), "v"(p1), "v"(p2), "v"(p3), "v"(p4), "v"(p5),
          "v"(p6), "v"(p7), "v"(p8), "v"(p9), "v"(p10), "v"(p11)
        : "memory");
}

#define PIDX(s, t, bt) ((((s) * NT) + (t)) * 4 + (bt))

// ---------------- small utility kernels ------------------------------------
__global__ void k_cvt(const float* __restrict__ src, uint16_t* __restrict__ dst, int n4) {
    int i = blockIdx.x * blockDim.x + threadIdx.x;
    if (i < n4) {
        float4 v = ((const float4*)src)[i];
        ushort4 o;
        o.x = f2bf(v.x); o.y = f2bf(v.y); o.z = f2bf(v.z); o.w = f2bf(v.w);
        ((ushort4*)dst)[i] = o;
    }
}
__global__ void k_zero(float* __restrict__ p, int n4) {
    int i = blockIdx.x * blockDim.x + threadIdx.x;
    if (i < n4) ((float4*)p)[i] = make_float4(0.f, 0.f, 0.f, 0.f);
}
__global__ void k_sentinel(float* __restrict__ out) {
    int i = blockIdx.x * blockDim.x + threadIdx.x;
    if (i < 1024) out[i] = -99999.0f;
}

// ---------------- encoder: encoded = mish(x @ enc_w^T + enc_b), bf16 out ----
__global__ __launch_bounds__(256) void k_encoder(
    const float* __restrict__ x, const float* __restrict__ enc_w,
    const float* __restrict__ enc_b, uint16_t* __restrict__ enc_out) {
    const int tid = threadIdx.x;
    const int lane = tid & 63, wid = tid >> 6;
    const int q = lane >> 4, l15 = lane & 15;
    const int wm = wid >> 1, wj = wid & 1;
    const int j0 = blockIdx.x * 128, b0 = blockIdx.y * 128;

    __shared__ uint16_t a_s[128 * 72];
    __shared__ uint16_t w_s[128 * 72];

#pragma unroll
    for (int jj = 0; jj < 8; ++jj) {
        int u = tid + jj * 256;
        int r = u >> 4, c4 = (u & 15) * 4;
        float4 va = *(const float4*)&x[(size_t)(b0 + r) * 64 + c4];
        float4 vw = *(const float4*)&enc_w[(size_t)(j0 + r) * 64 + c4];
        *(u64*)&a_s[r * 72 + c4] = pack4bf(va);
        *(u64*)&w_s[r * 72 + c4] = pack4bf(vw);
    }
    __syncthreads();

    floatx4 acc[4][4];
#pragma unroll
    for (int mi = 0; mi < 4; ++mi)
#pragma unroll
        for (int nf = 0; nf < 4; ++nf) acc[mi][nf] = (floatx4){0.f, 0.f, 0.f, 0.f};

#pragma unroll
    for (int kc = 0; kc < 2; ++kc) {
        short8 af[4], bfg[4];
#pragma unroll
        for (int mi = 0; mi < 4; ++mi)
            af[mi] = *(const short8*)&a_s[(wm * 64 + mi * 16 + l15) * 72 + kc * 32 + q * 8];
#pragma unroll
        for (int nf = 0; nf < 4; ++nf)
            bfg[nf] = *(const short8*)&w_s[(wj * 64 + nf * 16 + l15) * 72 + kc * 32 + q * 8];
#pragma unroll
        for (int mi = 0; mi < 4; ++mi)
#pragma unroll
            for (int nf = 0; nf < 4; ++nf)
                acc[mi][nf] = __builtin_amdgcn_mfma_f32_16x16x32_bf16(af[mi], bfg[nf], acc[mi][nf], 0, 0, 0);
    }

#pragma unroll
    for (int nf = 0; nf < 4; ++nf) {
        int j = j0 + wj * 64 + nf * 16 + l15;
        float eb = enc_b[j];
#pragma unroll
        for (int mi = 0; mi < 4; ++mi)
#pragma unroll
            for (int r = 0; r < 4; ++r) {
                int b = b0 + wm * 64 + mi * 16 + q * 4 + r;
                float v = acc[mi][nf][r] + eb;
                float sp = (v > 20.f) ? v : log1pf(expf(v));
                float m = v * tanhf(sp);
                enc_out[(size_t)b * 32768 + j] = f2bf(m);
            }
    }
}

// ---------------- shared memory layouts ------------------------------------
struct SGru {
    uint16_t wgi[96 * 524];   // [3g*32r][K(+12 pad)] — odd-16B stride for b64 reads
    uint16_t h_out[128 * 32]; // publish staging
};
struct SAtt {
    uint16_t hbf[6 * 16 * 264];
    float laP[3][3][16];
    float saT[4][16][17];
    float s_s[16], lg_s[16];
};
union SMem { SGru g; SAtt a; };

// ---------------- pipelined scan kernel ------------------------------------
// grid 224 x 256 thr.
//  b<192: GRU block: sd=b>>5, es=(b&31)>>2 (8 e-slices of 32), bt=b&3.
//         4 waves x 32 rows; gh weights in registers; gi weights in LDS
//         (stride 524, b64 fragment reads — conflict-spread).
//  b>=192: attention block ab=b-192 (32 blocks of 16 rows), 4 waves.
// Ring layout: slot[(t&7)] . plane[sd*8+es] (32KB) . row (64B) . col16.
__global__ __launch_bounds__(BTH, 1) void k_scan(
    const uint16_t* __restrict__ enc_bf,
    const uint16_t* __restrict__ wih0_bf, const uint16_t* __restrict__ wihL_bf,
    const uint16_t* __restrict__ whh_bf,
    const float* __restrict__ bih, const float* __restrict__ bhh,
    const uint16_t* __restrict__ law1_bf, const float* __restrict__ la_b1,
    const float* __restrict__ la_w2, const float* __restrict__ la_b2,
    const uint16_t* __restrict__ saw1_bf, const float* __restrict__ sa_b1,
    const float* __restrict__ sa_w2, const float* __restrict__ sa_b2,
    const float* __restrict__ ln_g, const float* __restrict__ ln_b,
    const float* __restrict__ fc_w, const float* __restrict__ fc_b,
    uint16_t* __restrict__ ring, int* produced, int* consumed,
    float* __restrict__ out) {
    const int blk = blockIdx.x;
    const int tid = threadIdx.x;
    const int w = tid >> 6;          // 0..3
    const int lane = tid & 63;
    const int q = lane >> 4, l15 = lane & 15;

    __shared__ SMem sm;

    if (blk < 192) {
        // =================== GRU stage block ===============================
        const int sd = blk >> 5;
        const int l = sd >> 1, dd = sd & 1;
        const int rem = blk & 31;
        const int es = rem >> 2;
        const int bt = rem & 3;
        const int row0 = bt * 128;
        const int Kgi = (l == 0) ? 128 : 512;
        const int ksh = (l == 0) ? 7 : 9;
        const int strgi = Kgi + 12;               // odd-16B byte stride (8-aligned)
        const uint16_t* wih = (l == 0) ? wih0_bf + (size_t)dd * NG * 128
                                       : wihL_bf + (size_t)((l - 1) * 2 + dd) * NG * 512;
        const uint16_t* whhp = whh_bf + (size_t)sd * NG * 256;
        const int ncons = (l < 2) ? 32 : 16;

        // ---- load gi weights into LDS (once), row-major, stride Kgi+12 ----
        // dst rows are 8B-aligned (stride*2 = 0 mod 8); write 8-u16 chunks
        // as two u64 stores (odd rows are not 16B-aligned by design).
        for (int flat = tid * 8; flat < 96 * Kgi; flat += BTH * 8) {
            int r = flat >> ksh, c = flat & (Kgi - 1);
            int g = r >> 5, rr = r & 31;
            int srow = g * 256 + es * 32 + rr;
            const uint16_t* src = &wih[(size_t)srow * Kgi + c];
            uint16_t* dst = &sm.g.wgi[r * strgi + c];
            *(u64*)dst = *(const u64*)src;
            *(u64*)(dst + 4) = *(const u64*)(src + 4);
        }
        // ---- gh weights: registers, loaded ONCE from global (r13/r14). ----
        short8 wghr[2][3][8];
#pragma unroll
        for (int sub = 0; sub < 2; ++sub)
#pragma unroll
            for (int g = 0; g < 3; ++g)
#pragma unroll
                for (int kc = 0; kc < 8; ++kc)
                    wghr[sub][g][kc] = *(const short8*)&whhp[
                        (size_t)(g * 256 + es * 32 + sub * 16 + l15) * 256 + kc * 32 + q * 8];

        float bRs[2], bZs[2], bNs[2], bHNs[2];
        {
            int ba = sd * NG;
#pragma unroll
            for (int sub = 0; sub < 2; ++sub) {
                int e = es * 32 + sub * 16 + l15;
                bRs[sub] = bih[ba + e] + bhh[ba + e];
                bZs[sub] = bih[ba + 256 + e] + bhh[ba + 256 + e];
                bNs[sub] = bih[ba + 512 + e];
                bHNs[sub] = bhh[ba + 512 + e];
            }
        }
        int wofs_gi[2][3];
#pragma unroll
        for (int sub = 0; sub < 2; ++sub)
#pragma unroll
            for (int g = 0; g < 3; ++g)
                wofs_gi[sub][g] = (g * 32 + sub * 16 + l15) * strgi + q * 8;
        // fp32 hidden carry: hreg[mt][sub][r], rows w*32 + mt*16 + q*4 + r
        float hreg[2][2][4];
#pragma unroll
        for (int mt = 0; mt < 2; ++mt)
#pragma unroll
            for (int sub = 0; sub < 2; ++sub)
#pragma unroll
                for (int r = 0; r < 4; ++r) hreg[mt][sub][r] = 0.f;

        const int myrowA = row0 + w * 32 + l15;     // A-tile 0 row; tile 1 = +16
        // loop-invariant per-lane plane offsets (bytes): kc*32KB + row*64 + q*16
        uint32_t voA[8], voB[8];
#pragma unroll
        for (int kc = 0; kc < 8; ++kc) {
            voA[kc] = (uint32_t)(kc * 32768 + myrowA * 64 + q * 16);
            voB[kc] = voA[kc] + 1024;               // +16 rows
        }
        const u64 ring_u = (u64)(uintptr_t)ring;
        __syncthreads();

        for (int t = 0; t < NT; ++t) {
            // ---- waits: distributed across waves (lane 0 of each wave) ----
            if (tid == 0) {
                if (t >= R_RING) poll_flag(&consumed[PIDX(sd, t - R_RING, bt)], ncons);
            } else if (tid == 64) {
                if (t >= 1) poll_flag(&produced[PIDX(sd, t - 1, bt)], 8);
            } else if (tid == 128) {
                if (l > 0) poll_flag(&produced[PIDX(2 * (l - 1), t, bt)], 8);
            } else if (tid == 192) {
                if (l > 0) poll_flag(&produced[PIDX(2 * (l - 1) + 1, t, bt)], 8);
            }
            __syncthreads();

            // ---- A-fragment loads (all STATIC av indices -> registers) ----
            // av[0..7]=gh mt0, av[8..15]=gh mt1,
            // av[16..31]=gi mt0, av[32..47]=gi mt1
            intx4 av[48];
            const u64 sb_gh = ring_u + (u64)((t - 1) & 7) * (RSLOT * 2) + ((u64)(sd * 8) << 15);
            if (l > 0) {
                const u64 sb0 = ring_u + (u64)(t & 7) * (RSLOT * 2) + ((u64)((2 * l - 2) * 8) << 15);
                if (t > 0) {
                    ld_plane8(sb_gh, voA[0], voA[1], voA[2], voA[3], voA[4], voA[5], voA[6], voA[7], av);
                    ld_plane8(sb_gh, voB[0], voB[1], voB[2], voB[3], voB[4], voB[5], voB[6], voB[7], av + 8);
                } else {
#pragma unroll
                    for (int i = 0; i < 16; ++i) av[i] = (intx4){0, 0, 0, 0};
                }
                ld_plane8(sb0, voA[0], voA[1], voA[2], voA[3], voA[4], voA[5], voA[6], voA[7], av + 16);
                ld_plane8(sb0 + (8u << 15), voA[0], voA[1], voA[2], voA[3], voA[4], voA[5], voA[6], voA[7], av + 24);
                ld_plane8(sb0, voB[0], voB[1], voB[2], voB[3], voB[4], voB[5], voB[6], voB[7], av + 32);
                ld_plane8(sb0 + (8u << 15), voB[0], voB[1], voB[2], voB[3], voB[4], voB[5], voB[6], voB[7], av + 40);
                if (t > 0) { wait_vm8(av); wait_vm8(av + 8); }
                wait_vm8(av + 16); wait_vm8(av + 24);
                wait_vm8(av + 32); wait_vm8(av + 40);
            } else {
                if (t > 0) {
                    ld_plane8(sb_gh, voA[0], voA[1], voA[2], voA[3], voA[4], voA[5], voA[6], voA[7], av);
                    ld_plane8(sb_gh, voB[0], voB[1], voB[2], voB[3], voB[4], voB[5], voB[6], voB[7], av + 8);
                } else {
#pragma unroll
                    for (int i = 0; i < 16; ++i) av[i] = (intx4){0, 0, 0, 0};
                }
                const uint16_t* eb0 = enc_bf + ((size_t)myrowA << 15) + t * 128 + q * 8;
                const uint16_t* eb1 = eb0 + ((size_t)16 << 15);
#pragma unroll
                for (int kc = 0; kc < 4; ++kc) {
                    __builtin_memcpy(&av[16 + kc], eb0 + kc * 32, 16);
                    __builtin_memcpy(&av[32 + kc], eb1 + kc * 32, 16);
                }
                if (t > 0) { wait_vm8(av); wait_vm8(av + 8); }
            }

            // ---- MFMA: each B-frag read feeds both A-tiles ----
            floatx4 aR[2][2], aZ[2][2], aNi[2][2], aNh[2][2];
#pragma unroll
            for (int mt = 0; mt < 2; ++mt)
#pragma unroll
                for (int sub = 0; sub < 2; ++sub) {
                    floatx4 z = (floatx4){0.f, 0.f, 0.f, 0.f};
                    aR[mt][sub] = z; aZ[mt][sub] = z; aNi[mt][sub] = z; aNh[mt][sub] = z;
                }
            if (l > 0) {
#pragma unroll
                for (int kc = 0; kc < 16; ++kc) {
                    short8 a0 = as_s8(av[16 + kc]);
                    short8 a1 = as_s8(av[32 + kc]);
#pragma unroll
                    for (int sub = 0; sub < 2; ++sub) {
                        short8 b0f = lds_frag(&sm.g.wgi[wofs_gi[sub][0] + kc * 32]);
                        short8 b1f = lds_frag(&sm.g.wgi[wofs_gi[sub][1] + kc * 32]);
                        short8 b2f = lds_frag(&sm.g.wgi[wofs_gi[sub][2] + kc * 32]);
                        aR[0][sub]  = __builtin_amdgcn_mfma_f32_16x16x32_bf16(a0, b0f, aR[0][sub], 0, 0, 0);
                        aR[1][sub]  = __builtin_amdgcn_mfma_f32_16x16x32_bf16(a1, b0f, aR[1][sub], 0, 0, 0);
                        aZ[0][sub]  = __builtin_amdgcn_mfma_f32_16x16x32_bf16(a0, b1f, aZ[0][sub], 0, 0, 0);
                        aZ[1][sub]  = __builtin_amdgcn_mfma_f32_16x16x32_bf16(a1, b1f, aZ[1][sub], 0, 0, 0);
                        aNi[0][sub] = __builtin_amdgcn_mfma_f32_16x16x32_bf16(a0, b2f, aNi[0][sub], 0, 0, 0);
                        aNi[1][sub] = __builtin_amdgcn_mfma_f32_16x16x32_bf16(a1, b2f, aNi[1][sub], 0, 0, 0);
                    }
                }
            } else {
#pragma unroll
                for (int kc = 0; kc < 4; ++kc) {
                    short8 a0 = as_s8(av[16 + kc]);
                    short8 a1 = as_s8(av[32 + kc]);
#pragma unroll
                    for (int sub = 0; sub < 2; ++sub) {
                        short8 b0f = lds_frag(&sm.g.wgi[wofs_gi[sub][0] + kc * 32]);
                        short8 b1f = lds_frag(&sm.g.wgi[wofs_gi[sub][1] + kc * 32]);
                        short8 b2f = lds_frag(&sm.g.wgi[wofs_gi[sub][2] + kc * 32]);
                        aR[0][sub]  = __builtin_amdgcn_mfma_f32_16x16x32_bf16(a0, b0f, aR[0][sub], 0, 0, 0);
                        aR[1][sub]  = __builtin_amdgcn_mfma_f32_16x16x32_bf16(a1, b0f, aR[1][sub], 0, 0, 0);
                        aZ[0][sub]  = __builtin_amdgcn_mfma_f32_16x16x32_bf16(a0, b1f, aZ[0][sub], 0, 0, 0);
                        aZ[1][sub]  = __builtin_amdgcn_mfma_f32_16x16x32_bf16(a1, b1f, aZ[1][sub], 0, 0, 0);
                        aNi[0][sub] = __builtin_amdgcn_mfma_f32_16x16x32_bf16(a0, b2f, aNi[0][sub], 0, 0, 0);
                        aNi[1][sub] = __builtin_amdgcn_mfma_f32_16x16x32_bf16(a1, b2f, aNi[1][sub], 0, 0, 0);
                    }
                }
            }
#pragma unroll
            for (int kc = 0; kc < 8; ++kc) {
                short8 a0 = as_s8(av[kc]);
                short8 a1 = as_s8(av[8 + kc]);
#pragma unroll
                for (int sub = 0; sub < 2; ++sub) {
                    short8 b0f = wghr[sub][0][kc];
                    short8 b1f = wghr[sub][1][kc];
                    short8 b2f = wghr[sub][2][kc];
                    aR[0][sub]  = __builtin_amdgcn_mfma_f32_16x16x32_bf16(a0, b0f, aR[0][sub], 0, 0, 0);
                    aR[1][sub]  = __builtin_amdgcn_mfma_f32_16x16x32_bf16(a1, b0f, aR[1][sub], 0, 0, 0);
                    aZ[0][sub]  = __builtin_amdgcn_mfma_f32_16x16x32_bf16(a0, b1f, aZ[0][sub], 0, 0, 0);
                    aZ[1][sub]  = __builtin_amdgcn_mfma_f32_16x16x32_bf16(a1, b1f, aZ[1][sub], 0, 0, 0);
                    aNh[0][sub] = __builtin_amdgcn_mfma_f32_16x16x32_bf16(a0, b2f, aNh[0][sub], 0, 0, 0);
                    aNh[1][sub] = __builtin_amdgcn_mfma_f32_16x16x32_bf16(a1, b2f, aNh[1][sub], 0, 0, 0);
                }
            }

            // ---- epilogue: gates + state update -> h_out ----
#pragma unroll
            for (int mt = 0; mt < 2; ++mt)
#pragma unroll
                for (int sub = 0; sub < 2; ++sub) {
#pragma unroll
                    for (int r = 0; r < 4; ++r) {
                        float rr = sigmoidf_(aR[mt][sub][r] + bRs[sub]);
                        float zz = sigmoidf_(aZ[mt][sub][r] + bZs[sub]);
                        float nn = tanhf(aNi[mt][sub][r] + bNs[sub] + rr * (aNh[mt][sub][r] + bHNs[sub]));
                        float hn = (1.f - zz) * nn + zz * hreg[mt][sub][r];
                        hreg[mt][sub][r] = hn;
                        sm.g.h_out[(w * 32 + mt * 16 + q * 4 + r) * 32 + sub * 16 + l15] = f2bf(hn);
                    }
                }
            __syncthreads();
            // ---- publish slice: contiguous 8KB burst per block (2 chunks/thr) ----
            {
                int i0 = tid, i1 = tid + 256;
                int r0 = i0 >> 2, p0 = i0 & 3;
                int r1 = i1 >> 2, p1 = i1 & 3;
                uint16_t* base = ring + (size_t)(t & 7) * RSLOT + ((size_t)(sd * 8 + es) << 14);
                uint16_t* d0 = base + (size_t)(row0 + r0) * 32 + p0 * 8;
                uint16_t* d1 = base + (size_t)(row0 + r1) * 32 + p1 * 8;
                st2_coh16_wait(d0, *(const intx4*)&sm.g.h_out[r0 * 32 + p0 * 8],
                               d1, *(const intx4*)&sm.g.h_out[r1 * 32 + p1 * 8]);
            }
            __syncthreads();   // every thread drained its own stores above
            if (tid == 0) {
                __hip_atomic_fetch_add(&produced[PIDX(sd, t, bt)], 1,
                                       __ATOMIC_RELAXED, __HIP_MEMORY_SCOPE_AGENT);
                if (l > 0) {
                    __hip_atomic_fetch_add(&consumed[PIDX(2 * l - 2, t, bt)], 1,
                                           __ATOMIC_RELAXED, __HIP_MEMORY_SCOPE_AGENT);
                    __hip_atomic_fetch_add(&consumed[PIDX(2 * l - 1, t, bt)], 1,
                                           __ATOMIC_RELAXED, __HIP_MEMORY_SCOPE_AGENT);
                }
                if (t >= 1)
                    __hip_atomic_fetch_add(&consumed[PIDX(sd, t - 1, bt)], 1,
                                           __ATOMIC_RELAXED, __HIP_MEMORY_SCOPE_AGENT);
            }
        }
        return;
    }

    // =================== attention block (16 rows, 4 waves) ================
    const int ab = blk - 192;
    const int b0 = ab * 16;
    const int bt = ab >> 3;
    // la tile slots: wave w handles tiles j = w + 4*s (s=0..2) where j<9
    float b1T[3], w2T[3];
#pragma unroll
    for (int s = 0; s < 3; ++s) {
        int j = w + 4 * s;
        if (j < 9) {
            int lA = j / 3, nfA = j % 3;
            b1T[s] = la_b1[lA * 48 + nfA * 16 + l15];
            w2T[s] = la_w2[lA * 48 + nfA * 16 + l15];
        } else { b1T[s] = 0.f; w2T[s] = 0.f; }
    }
    float nacc[32];
#pragma unroll
    for (int j = 0; j < 32; ++j) nacc[j] = 0.f;
    float m_r = -1e30f, d_r = 0.f;

    for (int t = 0; t < NT; ++t) {
        // ---- waits: distributed (w0 polls p4, w1 polls p5) ----
        if (tid == 0) {
            poll_flag(&produced[PIDX(4, t, bt)], 8);
        } else if (tid == 64) {
            poll_flag(&produced[PIDX(5, t, bt)], 8);
        }
        __syncthreads();
        // ---- stage all 6 states into hbf (12 chunks/thread) ----
        {
            const uint16_t* base = ring + (size_t)(t & 7) * RSLOT;
            const uint16_t* ps[12];
            int di[12];
#pragma unroll
            for (int i = 0; i < 12; ++i) {
                int f = i * 256 + tid;
                int s = f >> 9, r = (f >> 5) & 15, g = f & 31;
                int esx = g >> 2, c16 = g & 3;
                ps[i] = base + ((size_t)(s * 8 + esx) << 14) + (size_t)(b0 + r) * 32 + c16 * 8;
                di[i] = (s * 16 + r) * 264 + g * 8;
            }
            intx4 v[12];
            ld_sc12(ps[0], ps[1], ps[2], ps[3], ps[4], ps[5],
                    ps[6], ps[7], ps[8], ps[9], ps[10], ps[11], v);
#pragma unroll
            for (int i = 0; i < 12; ++i) *(intx4*)&sm.a.hbf[di[i]] = v[i];
        }
        __syncthreads();
        if (tid == 0) {
#pragma unroll
            for (int s = 0; s < 6; ++s)
                __hip_atomic_fetch_add(&consumed[PIDX(s, t, bt)], 1,
                                       __ATOMIC_RELAXED, __HIP_MEMORY_SCOPE_AGENT);
        }
        // ---- la tiles (up to 3 per wave) ----
#pragma unroll
        for (int s = 0; s < 3; ++s) {
            int j = w + 4 * s;
            if (j < 9) {
                int lA = j / 3, nfA = j % 3;
                floatx4 ac = (floatx4){0.f, 0.f, 0.f, 0.f};
#pragma unroll 2
                for (int kc = 0; kc < 512; kc += 32) {
                    int k = kc + q * 8;
                    int st = 2 * lA + (k >= 256 ? 1 : 0);
                    short8 afr = *(const short8*)&sm.a.hbf[(st * 16 + l15) * 264 + (k & 255)];
                    const uint16_t* wr = law1_bf + (size_t)(lA * 48 + nfA * 16 + l15) * 512 + k;
                    ac = __builtin_amdgcn_mfma_f32_16x16x32_bf16(afr, *(const short8*)wr, ac, 0, 0, 0);
                }
#pragma unroll
                for (int r = 0; r < 4; ++r) {
                    float v = geluf_(ac[r] + b1T[s]) * w2T[s];
                    v += __shfl_xor(v, 1, 64);
                    v += __shfl_xor(v, 2, 64);
                    v += __shfl_xor(v, 4, 64);
                    v += __shfl_xor(v, 8, 64);
                    if (l15 == 0) sm.a.laP[lA][nfA][q * 4 + r] = v;
                }
            }
        }
        // ---- sa tile nf = w (raw pre-acts) ----
        {
            floatx4 ac = (floatx4){0.f, 0.f, 0.f, 0.f};
#pragma unroll 2
            for (int kc = 0; kc < 512; kc += 32) {
                int k = kc + q * 8;
                int st = 4 + (k >= 256 ? 1 : 0);
                short8 afr = *(const short8*)&sm.a.hbf[(st * 16 + l15) * 264 + (k & 255)];
                const uint16_t* wr = saw1_bf + (size_t)(w * 16 + l15) * 512 + k;
                ac = __builtin_amdgcn_mfma_f32_16x16x32_bf16(afr, *(const short8*)wr, ac, 0, 0, 0);
            }
#pragma unroll
            for (int r = 0; r < 4; ++r) sm.a.saT[w][q * 4 + r][l15] = ac[r];
        }
        __syncthreads();
        // ---- combine: s and logit per row (wave 0) ----
        if (w == 0) {
            int row = l15;
            float sv = 0.f;
#pragma unroll
            for (int l = 0; l < 3; ++l)
                sv += sigmoidf_(sm.a.laP[l][0][row] + sm.a.laP[l][1][row] +
                                sm.a.laP[l][2][row] + la_b2[l]);
            float a2 = 0.f;
#pragma unroll
            for (int i = 0; i < 16; ++i) {
                int c = q * 16 + i;
                float pre = sv * sm.a.saT[q][row][i] + sa_b1[c];
                a2 += pre * sigmoidf_(pre) * sa_w2[c];
            }
            a2 += __shfl_xor(a2, 16, 64);
            a2 += __shfl_xor(a2, 32, 64);
            if (q == 0 && lane < 16) { sm.a.s_s[row] = sv; sm.a.lg_s[row] = a2 + sa_b2[0]; }
        }
        __syncthreads();
        // ---- online softmax update (wave w owns rows 4w..4w+3) ----
        {
            int myrow = 4 * w + (lane >> 4);
            int ci = lane & 15;
            float lg = sm.a.lg_s[myrow], sv = sm.a.s_s[myrow];
            float mn = fmaxf(m_r, lg);
            float cs = expf(m_r - mn);
            float e = expf(lg - mn);
            m_r = mn;
            d_r = d_r * cs + e;
            float wf = e * sv;
            int st = 4 + (ci >> 3);
            int c0 = (ci & 7) * 32;
            const uint16_t* hp = &sm.a.hbf[(size_t)(st * 16 + myrow) * 264 + c0];
            short8 o0 = *(const short8*)hp;
            short8 o1 = *(const short8*)(hp + 8);
            short8 o2 = *(const short8*)(hp + 16);
            short8 o3 = *(const short8*)(hp + 24);
#pragma unroll
            for (int j = 0; j < 8; ++j) {
                nacc[j]      = nacc[j]      * cs + wf * bf2f((uint16_t)o0[j]);
                nacc[8 + j]  = nacc[8 + j]  * cs + wf * bf2f((uint16_t)o1[j]);
                nacc[16 + j] = nacc[16 + j] * cs + wf * bf2f((uint16_t)o2[j]);
                nacc[24 + j] = nacc[24 + j] * cs + wf * bf2f((uint16_t)o3[j]);
            }
        }
        __syncthreads();   // protect hbf/s_s before next step's staging
    }

    // ---- finalize: context -> LN -> FC ----
    {
        int myrow = 4 * w + (lane >> 4);
        int ci = lane & 15;
        float dinv = 1.f / d_r;
        float cv[32];
        float s1 = 0.f, s2 = 0.f;
#pragma unroll
        for (int j = 0; j < 32; ++j) {
            cv[j] = nacc[j] * dinv;
            s1 += cv[j];
            s2 += cv[j] * cv[j];
        }
        s1 += __shfl_xor(s1, 1, 64);  s2 += __shfl_xor(s2, 1, 64);
        s1 += __shfl_xor(s1, 2, 64);  s2 += __shfl_xor(s2, 2, 64);
        s1 += __shfl_xor(s1, 4, 64);  s2 += __shfl_xor(s2, 4, 64);
        s1 += __shfl_xor(s1, 8, 64);  s2 += __shfl_xor(s2, 8, 64);
        float mean = s1 / 512.f;
        float var = s2 / 512.f - mean * mean;
        float rstd = rsqrtf(var + 1e-5f);
        float p0 = 0.f, p1 = 0.f;
#pragma unroll
        for (int j = 0; j < 32; ++j) {
            int g = ci * 32 + j;
            float nv = (cv[j] - mean) * rstd * ln_g[g] + ln_b[g];
            p0 += nv * fc_w[g];
            p1 += nv * fc_w[512 + g];
        }
        p0 += __shfl_xor(p0, 1, 64);  p1 += __shfl_xor(p1, 1, 64);
        p0 += __shfl_xor(p0, 2, 64);  p1 += __shfl_xor(p1, 2, 64);
        p0 += __shfl_xor(p0, 4, 64);  p1 += __shfl_xor(p1, 4, 64);
        p0 += __shfl_xor(p0, 8, 64);  p1 += __shfl_xor(p1, 8, 64);
        if ((lane & 15) == 0) {
            out[(b0 + myrow) * 2 + 0] = p0 + fc_b[0];
            out[(b0 + myrow) * 2 + 1] = p1 + fc_b[1];
        }
    }
}

// ---------------------------------------------------------------------------
extern "C" void kernel_launch(void* const* d_in, const int* in_sizes, int n_in,
                              void* d_out, int out_size, void* d_ws, size_t ws_size,
                              hipStream_t stream) {
    const float* x     = (const float*)d_in[0];
    const float* enc_w = (const float*)d_in[1];
    const float* enc_b = (const float*)d_in[2];
    const float* wih0  = (const float*)d_in[3];
    const float* wihL  = (const float*)d_in[4];
    const float* whh   = (const float*)d_in[5];
    const float* bih   = (const float*)d_in[6];
    const float* bhh   = (const float*)d_in[7];
    const float* la_w1 = (const float*)d_in[8];
    const float* la_b1 = (const float*)d_in[9];
    const float* la_w2 = (const float*)d_in[10];
    const float* la_b2 = (const float*)d_in[11];
    const float* sa_w1 = (const float*)d_in[12];
    const float* sa_b1 = (const float*)d_in[13];
    const float* sa_w2 = (const float*)d_in[14];
    const float* sa_b2 = (const float*)d_in[15];
    const float* ln_g  = (const float*)d_in[16];
    const float* ln_b  = (const float*)d_in[17];
    const float* fc_w  = (const float*)d_in[18];
    const float* fc_b  = (const float*)d_in[19];
    float* out = (float*)d_out;

    uint8_t* wsb = (uint8_t*)d_ws;
    size_t off = 0;
    auto alloc = [&](size_t bytes) -> void* {
        void* p = wsb + off;
        off += (bytes + 255) & ~(size_t)255;
        return p;
    };
    uint16_t* enc_bf  = (uint16_t*)alloc((size_t)NB * 32768 * 2);          // 33.55 MB
    uint16_t* wih0_bf = (uint16_t*)alloc((size_t)2 * NG * 128 * 2);        // 0.39 MB
    uint16_t* wihL_bf = (uint16_t*)alloc((size_t)2 * 2 * NG * 512 * 2);    // 3.15 MB
    uint16_t* whh_bf  = (uint16_t*)alloc((size_t)3 * 2 * NG * 256 * 2);    // 2.36 MB
    uint16_t* law1_bf = (uint16_t*)alloc((size_t)3 * 48 * 512 * 2);        // 0.15 MB
    uint16_t* saw1_bf = (uint16_t*)alloc((size_t)64 * 512 * 2);            // 0.07 MB
    uint16_t* ring    = (uint16_t*)alloc((size_t)R_RING * RSLOT * 2);      // 12.58 MB
    int*      produced= (int*)alloc((size_t)6 * NT * 4 * 4);               // 24 KB
    int*      consumed= (int*)alloc((size_t)6 * NT * 4 * 4);               // 24 KB
    // total ~52.3 MB

    if (ws_size < off) {
        k_sentinel<<<4, 256, 0, stream>>>(out);
        return;
    }

    auto cvt = [&](const float* s, uint16_t* dmem, int n) {
        int n4 = n / 4;
        k_cvt<<<(n4 + 255) / 256, 256, 0, stream>>>(s, dmem, n4);
    };
    cvt(wih0, wih0_bf, 196608);
    cvt(wihL, wihL_bf, 1572864);
    cvt(whh, whh_bf, 1179648);
    cvt(la_w1, law1_bf, 73728);
    cvt(sa_w1, saw1_bf, 32768);
    // zero produced+consumed (contiguous: 2 * 6144 ints = 3072 float4)
    k_zero<<<12, 256, 0, stream>>>((float*)produced, 3072);

    k_encoder<<<dim3(256, 4), 256, 0, stream>>>(x, enc_w, enc_b, enc_bf);

    k_scan<<<224, BTH, 0, stream>>>(enc_bf, wih0_bf, wihL_bf, whh_bf,
                                    bih, bhh, law1_bf, la_b1, la_w2, la_b2,
                                    saw1_bf, sa_b1, sa_w2, sa_b2,
                                    ln_g, ln_b, fc_w, fc_b,
                                    ring, produced, consumed, out);
}

// Round 12
// 3515.014 us; speedup vs baseline: 1.0929x; 1.0224x over previous
//
#include <hip/hip_runtime.h>
#include <stdint.h>

// ---------------------------------------------------------------------------
// GRUClassifier round 19: r18 base (3594us) + one-flag-per-cache-line.
// r18 post-mortem: bank conflicts collapsed 4.07e8 -> 6.7e7 (-84%) but dur
// moved only -53us -> conflicts were hidden; kernel is latency/sync-bound
// (HBM 3.5%, MfmaUtil 9%; bottom-up step work ~4us vs 14us interval).
// Suspect: flag FALSE SHARING. Old PIDX packed flags 4B apart: one 64B line
// held 4 bt-tiles x 4 timesteps of flags, concurrently hammered by ~8 adders
// and ~30 pollers across XCDs -> continuous MALL line ping-pong on the
// per-step critical path (poll -> compute -> publish -> add).
// Fix: PIDX stride *16 ints = one 64B line per flag. Pure indexing change:
// same protocol, same asm load/wait cluster byte-for-byte, bit-identical
// numerics. Flag arrays 24KB -> 384KB each (workspace fine); k_zero scaled.
// Canaries: absmax 0.00390625 exactly; conflicts ~6.7e7; WRITE_SIZE ~4.0e5.
// ---------------------------------------------------------------------------

typedef short short8 __attribute__((ext_vector_type(8)));
typedef float floatx4 __attribute__((ext_vector_type(4)));
typedef int intx4 __attribute__((ext_vector_type(4)));
typedef unsigned long long u64;

#define NB 512
#define NT 256
#define NH 256
#define NG 768
#define R_RING 8
#define RSLOT (6 * NB * NH)          // u16 elems per ring slot
#define BTH 256

__device__ __forceinline__ float bf2f(uint16_t v) {
    uint32_t u = ((uint32_t)v) << 16;
    float f;
    __builtin_memcpy(&f, &u, 4);
    return f;
}
__device__ __forceinline__ uint16_t f2bf(float f) {
    uint32_t u;
    __builtin_memcpy(&u, &f, 4);
    uint32_t r = (u + 0x7FFFu + ((u >> 16) & 1u)) >> 16;
    return (uint16_t)r;
}
__device__ __forceinline__ u64 pack4bf(float4 v) {
    u64 a = f2bf(v.x), b = f2bf(v.y), c = f2bf(v.z), d = f2bf(v.w);
    return a | (b << 16) | (c << 32) | (d << 48);
}
__device__ __forceinline__ float sigmoidf_(float x) { return 1.f / (1.f + expf(-x)); }
__device__ __forceinline__ float geluf_(float x) { return 0.5f * x * (1.f + erff(x * 0.70710678118f)); }
__device__ __forceinline__ short8 as_s8(intx4 v) { short8 r; __builtin_memcpy(&r, &v, 16); return r; }

// assemble a short8 B-fragment from two 8B LDS reads (8B-aligned rows)
__device__ __forceinline__ short8 lds_frag(const uint16_t* p) {
    u64 lo = *(const u64*)p;
    u64 hi = *(const u64*)(p + 4);
    short8 r;
    __builtin_memcpy(&r, &lo, 8);
    __builtin_memcpy((char*)&r + 8, &hi, 8);
    return r;
}

__device__ __forceinline__ void poll_flag(const int* p, int n) {
    while (__hip_atomic_load(p, __ATOMIC_RELAXED, __HIP_MEMORY_SCOPE_AGENT) < n)
        __builtin_amdgcn_s_sleep(1);
}

// two write-through 16B stores + own-thread drain
__device__ __forceinline__ void st2_coh16_wait(void* p0, intx4 v0, void* p1, intx4 v1) {
    asm volatile("global_store_dwordx4 %0, %1, off sc0 sc1\n\t"
                 "global_store_dwordx4 %2, %3, off sc0 sc1\n\t"
                 "s_waitcnt vmcnt(0)"
                 :: "v"(p0), "v"(v0), "v"(p1), "v"(v1) : "memory");
}

// 8 coherent loads from one plane-base (SGPR) with per-lane 32-bit offsets
__device__ __forceinline__ void ld_plane8(u64 sbase,
    uint32_t o0, uint32_t o1, uint32_t o2, uint32_t o3,
    uint32_t o4, uint32_t o5, uint32_t o6, uint32_t o7, intx4* v) {
    asm volatile(
        "global_load_dwordx4 %0, %8, %16 sc0 sc1\n\t"
        "global_load_dwordx4 %1, %9, %16 sc0 sc1\n\t"
        "global_load_dwordx4 %2, %10, %16 sc0 sc1\n\t"
        "global_load_dwordx4 %3, %11, %16 sc0 sc1\n\t"
        "global_load_dwordx4 %4, %12, %16 sc0 sc1\n\t"
        "global_load_dwordx4 %5, %13, %16 sc0 sc1\n\t"
        "global_load_dwordx4 %6, %14, %16 sc0 sc1\n\t"
        "global_load_dwordx4 %7, %15, %16 sc0 sc1"
        : "=&v"(v[0]), "=&v"(v[1]), "=&v"(v[2]), "=&v"(v[3]),
          "=&v"(v[4]), "=&v"(v[5]), "=&v"(v[6]), "=&v"(v[7])
        : "v"(o0), "v"(o1), "v"(o2), "v"(o3), "v"(o4), "v"(o5), "v"(o6), "v"(o7),
          "s"(sbase)
        : "memory");
}
// drain all outstanding vmem; ties 8 values so their uses can't be hoisted
__device__ __forceinline__ void wait_vm8(intx4* v) {
    asm volatile("s_waitcnt vmcnt(0)"
                 : "+v"(v[0]), "+v"(v[1]), "+v"(v[2]), "+v"(v[3]),
                   "+v"(v[4]), "+v"(v[5]), "+v"(v[6]), "+v"(v[7])
                 :: "memory");
}
// 12 scattered coherent loads (attention staging, 256-thread blocks)
__device__ __forceinline__ void ld_sc12(
    const uint16_t* p0, const uint16_t* p1, const uint16_t* p2,
    const uint16_t* p3, const uint16_t* p4, const uint16_t* p5,
    const uint16_t* p6, const uint16_t* p7, const uint16_t* p8,
    const uint16_t* p9, const uint16_t* p10, const uint16_t* p11, intx4* v) {
    asm volatile(
        "global_load_dwordx4 %0, %12, off sc0 sc1\n\t"
        "global_load_dwordx4 %1, %13, off sc0 sc1\n\t"
        "global_load_dwordx4 %2, %14, off sc0 sc1\n\t"
        "global_load_dwordx4 %3, %15, off sc0 sc1\n\t"
        "global_load_dwordx4 %4, %16, off sc0 sc1\n\t"
        "global_load_dwordx4 %5, %17, off sc0 sc1\n\t"
        "global_load_dwordx4 %6, %18, off sc0 sc1\n\t"
        "global_load_dwordx4 %7, %19, off sc0 sc1\n\t"
        "global_load_dwordx4 %8, %20, off sc0 sc1\n\t"
        "global_load_dwordx4 %9, %21, off sc0 sc1\n\t"
        "global_load_dwordx4 %10, %22, off sc0 sc1\n\t"
        "global_load_dwordx4 %11, %23, off sc0 sc1\n\t"
        "s_waitcnt vmcnt(0)"
        : "=&v"(v[0]), "=&v"(v[1]), "=&v"(v[2]), "=&v"(v[3]),
          "=&v"(v[4]), "=&v"(v[5]), "=&v"(v[6]), "=&v"(v[7]),
          "=&v"(v[8]), "=&v"(v[9]), "=&v"(v[10]), "=&v"(v[11])
        : "v"(p0), "v"(p1), "v"(p2), "v"(p3), "v"(p4), "v"(p5),
          "v"(p6), "v"(p7), "v"(p8), "v"(p9), "v"(p10), "v"(p11)
        : "memory");
}

// one flag per 64B cache line (16 ints) — kills false sharing on the
// produced/consumed lines that sit on every stage's per-step critical path.
#define PIDX(s, t, bt) (((((s) * NT) + (t)) * 4 + (bt)) * 16)

// ---------------- small utility kernels ------------------------------------
__global__ void k_cvt(const float* __restrict__ src, uint16_t* __restrict__ dst, int n4) {
    int i = blockIdx.x * blockDim.x + threadIdx.x;
    if (i < n4) {
        float4 v = ((const float4*)src)[i];
        ushort4 o;
        o.x = f2bf(v.x); o.y = f2bf(v.y); o.z = f2bf(v.z); o.w = f2bf(v.w);
        ((ushort4*)dst)[i] = o;
    }
}
__global__ void k_zero(float* __restrict__ p, int n4) {
    int i = blockIdx.x * blockDim.x + threadIdx.x;
    if (i < n4) ((float4*)p)[i] = make_float4(0.f, 0.f, 0.f, 0.f);
}
__global__ void k_sentinel(float* __restrict__ out) {
    int i = blockIdx.x * blockDim.x + threadIdx.x;
    if (i < 1024) out[i] = -99999.0f;
}

// ---------------- encoder: encoded = mish(x @ enc_w^T + enc_b), bf16 out ----
__global__ __launch_bounds__(256) void k_encoder(
    const float* __restrict__ x, const float* __restrict__ enc_w,
    const float* __restrict__ enc_b, uint16_t* __restrict__ enc_out) {
    const int tid = threadIdx.x;
    const int lane = tid & 63, wid = tid >> 6;
    const int q = lane >> 4, l15 = lane & 15;
    const int wm = wid >> 1, wj = wid & 1;
    const int j0 = blockIdx.x * 128, b0 = blockIdx.y * 128;

    __shared__ uint16_t a_s[128 * 72];
    __shared__ uint16_t w_s[128 * 72];

#pragma unroll
    for (int jj = 0; jj < 8; ++jj) {
        int u = tid + jj * 256;
        int r = u >> 4, c4 = (u & 15) * 4;
        float4 va = *(const float4*)&x[(size_t)(b0 + r) * 64 + c4];
        float4 vw = *(const float4*)&enc_w[(size_t)(j0 + r) * 64 + c4];
        *(u64*)&a_s[r * 72 + c4] = pack4bf(va);
        *(u64*)&w_s[r * 72 + c4] = pack4bf(vw);
    }
    __syncthreads();

    floatx4 acc[4][4];
#pragma unroll
    for (int mi = 0; mi < 4; ++mi)
#pragma unroll
        for (int nf = 0; nf < 4; ++nf) acc[mi][nf] = (floatx4){0.f, 0.f, 0.f, 0.f};

#pragma unroll
    for (int kc = 0; kc < 2; ++kc) {
        short8 af[4], bfg[4];
#pragma unroll
        for (int mi = 0; mi < 4; ++mi)
            af[mi] = *(const short8*)&a_s[(wm * 64 + mi * 16 + l15) * 72 + kc * 32 + q * 8];
#pragma unroll
        for (int nf = 0; nf < 4; ++nf)
            bfg[nf] = *(const short8*)&w_s[(wj * 64 + nf * 16 + l15) * 72 + kc * 32 + q * 8];
#pragma unroll
        for (int mi = 0; mi < 4; ++mi)
#pragma unroll
            for (int nf = 0; nf < 4; ++nf)
                acc[mi][nf] = __builtin_amdgcn_mfma_f32_16x16x32_bf16(af[mi], bfg[nf], acc[mi][nf], 0, 0, 0);
    }

#pragma unroll
    for (int nf = 0; nf < 4; ++nf) {
        int j = j0 + wj * 64 + nf * 16 + l15;
        float eb = enc_b[j];
#pragma unroll
        for (int mi = 0; mi < 4; ++mi)
#pragma unroll
            for (int r = 0; r < 4; ++r) {
                int b = b0 + wm * 64 + mi * 16 + q * 4 + r;
                float v = acc[mi][nf][r] + eb;
                float sp = (v > 20.f) ? v : log1pf(expf(v));
                float m = v * tanhf(sp);
                enc_out[(size_t)b * 32768 + j] = f2bf(m);
            }
    }
}

// ---------------- shared memory layouts ------------------------------------
struct SGru {
    uint16_t wgi[96 * 524];   // [3g*32r][K(+12 pad)] — odd-16B stride for b64 reads
    uint16_t h_out[128 * 32]; // publish staging
};
struct SAtt {
    uint16_t hbf[6 * 16 * 264];
    float laP[3][3][16];
    float saT[4][16][17];
    float s_s[16], lg_s[16];
};
union SMem { SGru g; SAtt a; };

// ---------------- pipelined scan kernel ------------------------------------
// grid 224 x 256 thr.
//  b<192: GRU block: sd=b>>5, es=(b&31)>>2 (8 e-slices of 32), bt=b&3.
//         4 waves x 32 rows; gh weights in registers; gi weights in LDS
//         (stride 524, b64 fragment reads — conflict-spread).
//  b>=192: attention block ab=b-192 (32 blocks of 16 rows), 4 waves.
// Ring layout: slot[(t&7)] . plane[sd*8+es] (32KB) . row (64B) . col16.
__global__ __launch_bounds__(BTH, 1) void k_scan(
    const uint16_t* __restrict__ enc_bf,
    const uint16_t* __restrict__ wih0_bf, const uint16_t* __restrict__ wihL_bf,
    const uint16_t* __restrict__ whh_bf,
    const float* __restrict__ bih, const float* __restrict__ bhh,
    const uint16_t* __restrict__ law1_bf, const float* __restrict__ la_b1,
    const float* __restrict__ la_w2, const float* __restrict__ la_b2,
    const uint16_t* __restrict__ saw1_bf, const float* __restrict__ sa_b1,
    const float* __restrict__ sa_w2, const float* __restrict__ sa_b2,
    const float* __restrict__ ln_g, const float* __restrict__ ln_b,
    const float* __restrict__ fc_w, const float* __restrict__ fc_b,
    uint16_t* __restrict__ ring, int* produced, int* consumed,
    float* __restrict__ out) {
    const int blk = blockIdx.x;
    const int tid = threadIdx.x;
    const int w = tid >> 6;          // 0..3
    const int lane = tid & 63;
    const int q = lane >> 4, l15 = lane & 15;

    __shared__ SMem sm;

    if (blk < 192) {
        // =================== GRU stage block ===============================
        const int sd = blk >> 5;
        const int l = sd >> 1, dd = sd & 1;
        const int rem = blk & 31;
        const int es = rem >> 2;
        const int bt = rem & 3;
        const int row0 = bt * 128;
        const int Kgi = (l == 0) ? 128 : 512;
        const int ksh = (l == 0) ? 7 : 9;
        const int strgi = Kgi + 12;               // odd-16B byte stride (8-aligned)
        const uint16_t* wih = (l == 0) ? wih0_bf + (size_t)dd * NG * 128
                                       : wihL_bf + (size_t)((l - 1) * 2 + dd) * NG * 512;
        const uint16_t* whhp = whh_bf + (size_t)sd * NG * 256;
        const int ncons = (l < 2) ? 32 : 16;

        // ---- load gi weights into LDS (once), row-major, stride Kgi+12 ----
        for (int flat = tid * 8; flat < 96 * Kgi; flat += BTH * 8) {
            int r = flat >> ksh, c = flat & (Kgi - 1);
            int g = r >> 5, rr = r & 31;
            int srow = g * 256 + es * 32 + rr;
            const uint16_t* src = &wih[(size_t)srow * Kgi + c];
            uint16_t* dst = &sm.g.wgi[r * strgi + c];
            *(u64*)dst = *(const u64*)src;
            *(u64*)(dst + 4) = *(const u64*)(src + 4);
        }
        // ---- gh weights: registers, loaded ONCE from global (r13/r14). ----
        short8 wghr[2][3][8];
#pragma unroll
        for (int sub = 0; sub < 2; ++sub)
#pragma unroll
            for (int g = 0; g < 3; ++g)
#pragma unroll
                for (int kc = 0; kc < 8; ++kc)
                    wghr[sub][g][kc] = *(const short8*)&whhp[
                        (size_t)(g * 256 + es * 32 + sub * 16 + l15) * 256 + kc * 32 + q * 8];

        float bRs[2], bZs[2], bNs[2], bHNs[2];
        {
            int ba = sd * NG;
#pragma unroll
            for (int sub = 0; sub < 2; ++sub) {
                int e = es * 32 + sub * 16 + l15;
                bRs[sub] = bih[ba + e] + bhh[ba + e];
                bZs[sub] = bih[ba + 256 + e] + bhh[ba + 256 + e];
                bNs[sub] = bih[ba + 512 + e];
                bHNs[sub] = bhh[ba + 512 + e];
            }
        }
        int wofs_gi[2][3];
#pragma unroll
        for (int sub = 0; sub < 2; ++sub)
#pragma unroll
            for (int g = 0; g < 3; ++g)
                wofs_gi[sub][g] = (g * 32 + sub * 16 + l15) * strgi + q * 8;
        // fp32 hidden carry: hreg[mt][sub][r], rows w*32 + mt*16 + q*4 + r
        float hreg[2][2][4];
#pragma unroll
        for (int mt = 0; mt < 2; ++mt)
#pragma unroll
            for (int sub = 0; sub < 2; ++sub)
#pragma unroll
                for (int r = 0; r < 4; ++r) hreg[mt][sub][r] = 0.f;

        const int myrowA = row0 + w * 32 + l15;     // A-tile 0 row; tile 1 = +16
        // loop-invariant per-lane plane offsets (bytes): kc*32KB + row*64 + q*16
        uint32_t voA[8], voB[8];
#pragma unroll
        for (int kc = 0; kc < 8; ++kc) {
            voA[kc] = (uint32_t)(kc * 32768 + myrowA * 64 + q * 16);
            voB[kc] = voA[kc] + 1024;               // +16 rows
        }
        const u64 ring_u = (u64)(uintptr_t)ring;
        __syncthreads();

        for (int t = 0; t < NT; ++t) {
            // ---- waits: distributed across waves (lane 0 of each wave) ----
            if (tid == 0) {
                if (t >= R_RING) poll_flag(&consumed[PIDX(sd, t - R_RING, bt)], ncons);
            } else if (tid == 64) {
                if (t >= 1) poll_flag(&produced[PIDX(sd, t - 1, bt)], 8);
            } else if (tid == 128) {
                if (l > 0) poll_flag(&produced[PIDX(2 * (l - 1), t, bt)], 8);
            } else if (tid == 192) {
                if (l > 0) poll_flag(&produced[PIDX(2 * (l - 1) + 1, t, bt)], 8);
            }
            __syncthreads();

            // ---- A-fragment loads (all STATIC av indices -> registers) ----
            // av[0..7]=gh mt0, av[8..15]=gh mt1,
            // av[16..31]=gi mt0, av[32..47]=gi mt1
            intx4 av[48];
            const u64 sb_gh = ring_u + (u64)((t - 1) & 7) * (RSLOT * 2) + ((u64)(sd * 8) << 15);
            if (l > 0) {
                const u64 sb0 = ring_u + (u64)(t & 7) * (RSLOT * 2) + ((u64)((2 * l - 2) * 8) << 15);
                if (t > 0) {
                    ld_plane8(sb_gh, voA[0], voA[1], voA[2], voA[3], voA[4], voA[5], voA[6], voA[7], av);
                    ld_plane8(sb_gh, voB[0], voB[1], voB[2], voB[3], voB[4], voB[5], voB[6], voB[7], av + 8);
                } else {
#pragma unroll
                    for (int i = 0; i < 16; ++i) av[i] = (intx4){0, 0, 0, 0};
                }
                ld_plane8(sb0, voA[0], voA[1], voA[2], voA[3], voA[4], voA[5], voA[6], voA[7], av + 16);
                ld_plane8(sb0 + (8u << 15), voA[0], voA[1], voA[2], voA[3], voA[4], voA[5], voA[6], voA[7], av + 24);
                ld_plane8(sb0, voB[0], voB[1], voB[2], voB[3], voB[4], voB[5], voB[6], voB[7], av + 32);
                ld_plane8(sb0 + (8u << 15), voB[0], voB[1], voB[2], voB[3], voB[4], voB[5], voB[6], voB[7], av + 40);
                if (t > 0) { wait_vm8(av); wait_vm8(av + 8); }
                wait_vm8(av + 16); wait_vm8(av + 24);
                wait_vm8(av + 32); wait_vm8(av + 40);
            } else {
                if (t > 0) {
                    ld_plane8(sb_gh, voA[0], voA[1], voA[2], voA[3], voA[4], voA[5], voA[6], voA[7], av);
                    ld_plane8(sb_gh, voB[0], voB[1], voB[2], voB[3], voB[4], voB[5], voB[6], voB[7], av + 8);
                } else {
#pragma unroll
                    for (int i = 0; i < 16; ++i) av[i] = (intx4){0, 0, 0, 0};
                }
                const uint16_t* eb0 = enc_bf + ((size_t)myrowA << 15) + t * 128 + q * 8;
                const uint16_t* eb1 = eb0 + ((size_t)16 << 15);
#pragma unroll
                for (int kc = 0; kc < 4; ++kc) {
                    __builtin_memcpy(&av[16 + kc], eb0 + kc * 32, 16);
                    __builtin_memcpy(&av[32 + kc], eb1 + kc * 32, 16);
                }
                if (t > 0) { wait_vm8(av); wait_vm8(av + 8); }
            }

            // ---- MFMA: each B-frag read feeds both A-tiles ----
            floatx4 aR[2][2], aZ[2][2], aNi[2][2], aNh[2][2];
#pragma unroll
            for (int mt = 0; mt < 2; ++mt)
#pragma unroll
                for (int sub = 0; sub < 2; ++sub) {
                    floatx4 z = (floatx4){0.f, 0.f, 0.f, 0.f};
                    aR[mt][sub] = z; aZ[mt][sub] = z; aNi[mt][sub] = z; aNh[mt][sub] = z;
                }
            if (l > 0) {
#pragma unroll
                for (int kc = 0; kc < 16; ++kc) {
                    short8 a0 = as_s8(av[16 + kc]);
                    short8 a1 = as_s8(av[32 + kc]);
#pragma unroll
                    for (int sub = 0; sub < 2; ++sub) {
                        short8 b0f = lds_frag(&sm.g.wgi[wofs_gi[sub][0] + kc * 32]);
                        short8 b1f = lds_frag(&sm.g.wgi[wofs_gi[sub][1] + kc * 32]);
                        short8 b2f = lds_frag(&sm.g.wgi[wofs_gi[sub][2] + kc * 32]);
                        aR[0][sub]  = __builtin_amdgcn_mfma_f32_16x16x32_bf16(a0, b0f, aR[0][sub], 0, 0, 0);
                        aR[1][sub]  = __builtin_amdgcn_mfma_f32_16x16x32_bf16(a1, b0f, aR[1][sub], 0, 0, 0);
                        aZ[0][sub]  = __builtin_amdgcn_mfma_f32_16x16x32_bf16(a0, b1f, aZ[0][sub], 0, 0, 0);
                        aZ[1][sub]  = __builtin_amdgcn_mfma_f32_16x16x32_bf16(a1, b1f, aZ[1][sub], 0, 0, 0);
                        aNi[0][sub] = __builtin_amdgcn_mfma_f32_16x16x32_bf16(a0, b2f, aNi[0][sub], 0, 0, 0);
                        aNi[1][sub] = __builtin_amdgcn_mfma_f32_16x16x32_bf16(a1, b2f, aNi[1][sub], 0, 0, 0);
                    }
                }
            } else {
#pragma unroll
                for (int kc = 0; kc < 4; ++kc) {
                    short8 a0 = as_s8(av[16 + kc]);
                    short8 a1 = as_s8(av[32 + kc]);
#pragma unroll
                    for (int sub = 0; sub < 2; ++sub) {
                        short8 b0f = lds_frag(&sm.g.wgi[wofs_gi[sub][0] + kc * 32]);
                        short8 b1f = lds_frag(&sm.g.wgi[wofs_gi[sub][1] + kc * 32]);
                        short8 b2f = lds_frag(&sm.g.wgi[wofs_gi[sub][2] + kc * 32]);
                        aR[0][sub]  = __builtin_amdgcn_mfma_f32_16x16x32_bf16(a0, b0f, aR[0][sub], 0, 0, 0);
                        aR[1][sub]  = __builtin_amdgcn_mfma_f32_16x16x32_bf16(a1, b0f, aR[1][sub], 0, 0, 0);
                        aZ[0][sub]  = __builtin_amdgcn_mfma_f32_16x16x32_bf16(a0, b1f, aZ[0][sub], 0, 0, 0);
                        aZ[1][sub]  = __builtin_amdgcn_mfma_f32_16x16x32_bf16(a1, b1f, aZ[1][sub], 0, 0, 0);
                        aNi[0][sub] = __builtin_amdgcn_mfma_f32_16x16x32_bf16(a0, b2f, aNi[0][sub], 0, 0, 0);
                        aNi[1][sub] = __builtin_amdgcn_mfma_f32_16x16x32_bf16(a1, b2f, aNi[1][sub], 0, 0, 0);
                    }
                }
            }
#pragma unroll
            for (int kc = 0; kc < 8; ++kc) {
                short8 a0 = as_s8(av[kc]);
                short8 a1 = as_s8(av[8 + kc]);
#pragma unroll
                for (int sub = 0; sub < 2; ++sub) {
                    short8 b0f = wghr[sub][0][kc];
                    short8 b1f = wghr[sub][1][kc];
                    short8 b2f = wghr[sub][2][kc];
                    aR[0][sub]  = __builtin_amdgcn_mfma_f32_16x16x32_bf16(a0, b0f, aR[0][sub], 0, 0, 0);
                    aR[1][sub]  = __builtin_amdgcn_mfma_f32_16x16x32_bf16(a1, b0f, aR[1][sub], 0, 0, 0);
                    aZ[0][sub]  = __builtin_amdgcn_mfma_f32_16x16x32_bf16(a0, b1f, aZ[0][sub], 0, 0, 0);
                    aZ[1][sub]  = __builtin_amdgcn_mfma_f32_16x16x32_bf16(a1, b1f, aZ[1][sub], 0, 0, 0);
                    aNh[0][sub] = __builtin_amdgcn_mfma_f32_16x16x32_bf16(a0, b2f, aNh[0][sub], 0, 0, 0);
                    aNh[1][sub] = __builtin_amdgcn_mfma_f32_16x16x32_bf16(a1, b2f, aNh[1][sub], 0, 0, 0);
                }
            }

            // ---- epilogue: gates + state update -> h_out ----
#pragma unroll
            for (int mt = 0; mt < 2; ++mt)
#pragma unroll
                for (int sub = 0; sub < 2; ++sub) {
#pragma unroll
                    for (int r = 0; r < 4; ++r) {
                        float rr = sigmoidf_(aR[mt][sub][r] + bRs[sub]);
                        float zz = sigmoidf_(aZ[mt][sub][r] + bZs[sub]);
                        float nn = tanhf(aNi[mt][sub][r] + bNs[sub] + rr * (aNh[mt][sub][r] + bHNs[sub]));
                        float hn = (1.f - zz) * nn + zz * hreg[mt][sub][r];
                        hreg[mt][sub][r] = hn;
                        sm.g.h_out[(w * 32 + mt * 16 + q * 4 + r) * 32 + sub * 16 + l15] = f2bf(hn);
                    }
                }
            __syncthreads();
            // ---- publish slice: contiguous 8KB burst per block (2 chunks/thr) ----
            {
                int i0 = tid, i1 = tid + 256;
                int r0 = i0 >> 2, p0 = i0 & 3;
                int r1 = i1 >> 2, p1 = i1 & 3;
                uint16_t* base = ring + (size_t)(t & 7) * RSLOT + ((size_t)(sd * 8 + es) << 14);
                uint16_t* d0 = base + (size_t)(row0 + r0) * 32 + p0 * 8;
                uint16_t* d1 = base + (size_t)(row0 + r1) * 32 + p1 * 8;
                st2_coh16_wait(d0, *(const intx4*)&sm.g.h_out[r0 * 32 + p0 * 8],
                               d1, *(const intx4*)&sm.g.h_out[r1 * 32 + p1 * 8]);
            }
            __syncthreads();   // every thread drained its own stores above
            if (tid == 0) {
                __hip_atomic_fetch_add(&produced[PIDX(sd, t, bt)], 1,
                                       __ATOMIC_RELAXED, __HIP_MEMORY_SCOPE_AGENT);
                if (l > 0) {
                    __hip_atomic_fetch_add(&consumed[PIDX(2 * l - 2, t, bt)], 1,
                                           __ATOMIC_RELAXED, __HIP_MEMORY_SCOPE_AGENT);
                    __hip_atomic_fetch_add(&consumed[PIDX(2 * l - 1, t, bt)], 1,
                                           __ATOMIC_RELAXED, __HIP_MEMORY_SCOPE_AGENT);
                }
                if (t >= 1)
                    __hip_atomic_fetch_add(&consumed[PIDX(sd, t - 1, bt)], 1,
                                           __ATOMIC_RELAXED, __HIP_MEMORY_SCOPE_AGENT);
            }
        }
        return;
    }

    // =================== attention block (16 rows, 4 waves) ================
    const int ab = blk - 192;
    const int b0 = ab * 16;
    const int bt = ab >> 3;
    // la tile slots: wave w handles tiles j = w + 4*s (s=0..2) where j<9
    float b1T[3], w2T[3];
#pragma unroll
    for (int s = 0; s < 3; ++s) {
        int j = w + 4 * s;
        if (j < 9) {
            int lA = j / 3, nfA = j % 3;
            b1T[s] = la_b1[lA * 48 + nfA * 16 + l15];
            w2T[s] = la_w2[lA * 48 + nfA * 16 + l15];
        } else { b1T[s] = 0.f; w2T[s] = 0.f; }
    }
    float nacc[32];
#pragma unroll
    for (int j = 0; j < 32; ++j) nacc[j] = 0.f;
    float m_r = -1e30f, d_r = 0.f;

    for (int t = 0; t < NT; ++t) {
        // ---- waits: distributed (w0 polls p4, w1 polls p5) ----
        if (tid == 0) {
            poll_flag(&produced[PIDX(4, t, bt)], 8);
        } else if (tid == 64) {
            poll_flag(&produced[PIDX(5, t, bt)], 8);
        }
        __syncthreads();
        // ---- stage all 6 states into hbf (12 chunks/thread) ----
        {
            const uint16_t* base = ring + (size_t)(t & 7) * RSLOT;
            const uint16_t* ps[12];
            int di[12];
#pragma unroll
            for (int i = 0; i < 12; ++i) {
                int f = i * 256 + tid;
                int s = f >> 9, r = (f >> 5) & 15, g = f & 31;
                int esx = g >> 2, c16 = g & 3;
                ps[i] = base + ((size_t)(s * 8 + esx) << 14) + (size_t)(b0 + r) * 32 + c16 * 8;
                di[i] = (s * 16 + r) * 264 + g * 8;
            }
            intx4 v[12];
            ld_sc12(ps[0], ps[1], ps[2], ps[3], ps[4], ps[5],
                    ps[6], ps[7], ps[8], ps[9], ps[10], ps[11], v);
#pragma unroll
            for (int i = 0; i < 12; ++i) *(intx4*)&sm.a.hbf[di[i]] = v[i];
        }
        __syncthreads();
        if (tid == 0) {
#pragma unroll
            for (int s = 0; s < 6; ++s)
                __hip_atomic_fetch_add(&consumed[PIDX(s, t, bt)], 1,
                                       __ATOMIC_RELAXED, __HIP_MEMORY_SCOPE_AGENT);
        }
        // ---- la tiles (up to 3 per wave) ----
#pragma unroll
        for (int s = 0; s < 3; ++s) {
            int j = w + 4 * s;
            if (j < 9) {
                int lA = j / 3, nfA = j % 3;
                floatx4 ac = (floatx4){0.f, 0.f, 0.f, 0.f};
#pragma unroll 2
                for (int kc = 0; kc < 512; kc += 32) {
                    int k = kc + q * 8;
                    int st = 2 * lA + (k >= 256 ? 1 : 0);
                    short8 afr = *(const short8*)&sm.a.hbf[(st * 16 + l15) * 264 + (k & 255)];
                    const uint16_t* wr = law1_bf + (size_t)(lA * 48 + nfA * 16 + l15) * 512 + k;
                    ac = __builtin_amdgcn_mfma_f32_16x16x32_bf16(afr, *(const short8*)wr, ac, 0, 0, 0);
                }
#pragma unroll
                for (int r = 0; r < 4; ++r) {
                    float v = geluf_(ac[r] + b1T[s]) * w2T[s];
                    v += __shfl_xor(v, 1, 64);
                    v += __shfl_xor(v, 2, 64);
                    v += __shfl_xor(v, 4, 64);
                    v += __shfl_xor(v, 8, 64);
                    if (l15 == 0) sm.a.laP[lA][nfA][q * 4 + r] = v;
                }
            }
        }
        // ---- sa tile nf = w (raw pre-acts) ----
        {
            floatx4 ac = (floatx4){0.f, 0.f, 0.f, 0.f};
#pragma unroll 2
            for (int kc = 0; kc < 512; kc += 32) {
                int k = kc + q * 8;
                int st = 4 + (k >= 256 ? 1 : 0);
                short8 afr = *(const short8*)&sm.a.hbf[(st * 16 + l15) * 264 + (k & 255)];
                const uint16_t* wr = saw1_bf + (size_t)(w * 16 + l15) * 512 + k;
                ac = __builtin_amdgcn_mfma_f32_16x16x32_bf16(afr, *(const short8*)wr, ac, 0, 0, 0);
            }
#pragma unroll
            for (int r = 0; r < 4; ++r) sm.a.saT[w][q * 4 + r][l15] = ac[r];
        }
        __syncthreads();
        // ---- combine: s and logit per row (wave 0) ----
        if (w == 0) {
            int row = l15;
            float sv = 0.f;
#pragma unroll
            for (int l = 0; l < 3; ++l)
                sv += sigmoidf_(sm.a.laP[l][0][row] + sm.a.laP[l][1][row] +
                                sm.a.laP[l][2][row] + la_b2[l]);
            float a2 = 0.f;
#pragma unroll
            for (int i = 0; i < 16; ++i) {
                int c = q * 16 + i;
                float pre = sv * sm.a.saT[q][row][i] + sa_b1[c];
                a2 += pre * sigmoidf_(pre) * sa_w2[c];
            }
            a2 += __shfl_xor(a2, 16, 64);
            a2 += __shfl_xor(a2, 32, 64);
            if (q == 0 && lane < 16) { sm.a.s_s[row] = sv; sm.a.lg_s[row] = a2 + sa_b2[0]; }
        }
        __syncthreads();
        // ---- online softmax update (wave w owns rows 4w..4w+3) ----
        {
            int myrow = 4 * w + (lane >> 4);
            int ci = lane & 15;
            float lg = sm.a.lg_s[myrow], sv = sm.a.s_s[myrow];
            float mn = fmaxf(m_r, lg);
            float cs = expf(m_r - mn);
            float e = expf(lg - mn);
            m_r = mn;
            d_r = d_r * cs + e;
            float wf = e * sv;
            int st = 4 + (ci >> 3);
            int c0 = (ci & 7) * 32;
            const uint16_t* hp = &sm.a.hbf[(size_t)(st * 16 + myrow) * 264 + c0];
            short8 o0 = *(const short8*)hp;
            short8 o1 = *(const short8*)(hp + 8);
            short8 o2 = *(const short8*)(hp + 16);
            short8 o3 = *(const short8*)(hp + 24);
#pragma unroll
            for (int j = 0; j < 8; ++j) {
                nacc[j]      = nacc[j]      * cs + wf * bf2f((uint16_t)o0[j]);
                nacc[8 + j]  = nacc[8 + j]  * cs + wf * bf2f((uint16_t)o1[j]);
                nacc[16 + j] = nacc[16 + j] * cs + wf * bf2f((uint16_t)o2[j]);
                nacc[24 + j] = nacc[24 + j] * cs + wf * bf2f((uint16_t)o3[j]);
            }
        }
        __syncthreads();   // protect hbf/s_s before next step's staging
    }

    // ---- finalize: context -> LN -> FC ----
    {
        int myrow = 4 * w + (lane >> 4);
        int ci = lane & 15;
        float dinv = 1.f / d_r;
        float cv[32];
        float s1 = 0.f, s2 = 0.f;
#pragma unroll
        for (int j = 0; j < 32; ++j) {
            cv[j] = nacc[j] * dinv;
            s1 += cv[j];
            s2 += cv[j] * cv[j];
        }
        s1 += __shfl_xor(s1, 1, 64);  s2 += __shfl_xor(s2, 1, 64);
        s1 += __shfl_xor(s1, 2, 64);  s2 += __shfl_xor(s2, 2, 64);
        s1 += __shfl_xor(s1, 4, 64);  s2 += __shfl_xor(s2, 4, 64);
        s1 += __shfl_xor(s1, 8, 64);  s2 += __shfl_xor(s2, 8, 64);
        float mean = s1 / 512.f;
        float var = s2 / 512.f - mean * mean;
        float rstd = rsqrtf(var + 1e-5f);
        float p0 = 0.f, p1 = 0.f;
#pragma unroll
        for (int j = 0; j < 32; ++j) {
            int g = ci * 32 + j;
            float nv = (cv[j] - mean) * rstd * ln_g[g] + ln_b[g];
            p0 += nv * fc_w[g];
            p1 += nv * fc_w[512 + g];
        }
        p0 += __shfl_xor(p0, 1, 64);  p1 += __shfl_xor(p1, 1, 64);
        p0 += __shfl_xor(p0, 2, 64);  p1 += __shfl_xor(p1, 2, 64);
        p0 += __shfl_xor(p0, 4, 64);  p1 += __shfl_xor(p1, 4, 64);
        p0 += __shfl_xor(p0, 8, 64);  p1 += __shfl_xor(p1, 8, 64);
        if ((lane & 15) == 0) {
            out[(b0 + myrow) * 2 + 0] = p0 + fc_b[0];
            out[(b0 + myrow) * 2 + 1] = p1 + fc_b[1];
        }
    }
}

// ---------------------------------------------------------------------------
extern "C" void kernel_launch(void* const* d_in, const int* in_sizes, int n_in,
                              void* d_out, int out_size, void* d_ws, size_t ws_size,
                              hipStream_t stream) {
    const float* x     = (const float*)d_in[0];
    const float* enc_w = (const float*)d_in[1];
    const float* enc_b = (const float*)d_in[2];
    const float* wih0  = (const float*)d_in[3];
    const float* wihL  = (const float*)d_in[4];
    const float* whh   = (const float*)d_in[5];
    const float* bih   = (const float*)d_in[6];
    const float* bhh   = (const float*)d_in[7];
    const float* la_w1 = (const float*)d_in[8];
    const float* la_b1 = (const float*)d_in[9];
    const float* la_w2 = (const float*)d_in[10];
    const float* la_b2 = (const float*)d_in[11];
    const float* sa_w1 = (const float*)d_in[12];
    const float* sa_b1 = (const float*)d_in[13];
    const float* sa_w2 = (const float*)d_in[14];
    const float* sa_b2 = (const float*)d_in[15];
    const float* ln_g  = (const float*)d_in[16];
    const float* ln_b  = (const float*)d_in[17];
    const float* fc_w  = (const float*)d_in[18];
    const float* fc_b  = (const float*)d_in[19];
    float* out = (float*)d_out;

    uint8_t* wsb = (uint8_t*)d_ws;
    size_t off = 0;
    auto alloc = [&](size_t bytes) -> void* {
        void* p = wsb + off;
        off += (bytes + 255) & ~(size_t)255;
        return p;
    };
    uint16_t* enc_bf  = (uint16_t*)alloc((size_t)NB * 32768 * 2);          // 33.55 MB
    uint16_t* wih0_bf = (uint16_t*)alloc((size_t)2 * NG * 128 * 2);        // 0.39 MB
    uint16_t* wihL_bf = (uint16_t*)alloc((size_t)2 * 2 * NG * 512 * 2);    // 3.15 MB
    uint16_t* whh_bf  = (uint16_t*)alloc((size_t)3 * 2 * NG * 256 * 2);    // 2.36 MB
    uint16_t* law1_bf = (uint16_t*)alloc((size_t)3 * 48 * 512 * 2);        // 0.15 MB
    uint16_t* saw1_bf = (uint16_t*)alloc((size_t)64 * 512 * 2);            // 0.07 MB
    uint16_t* ring    = (uint16_t*)alloc((size_t)R_RING * RSLOT * 2);      // 12.58 MB
    int*      produced= (int*)alloc((size_t)6 * NT * 4 * 64);              // 384 KB (64B/flag)
    int*      consumed= (int*)alloc((size_t)6 * NT * 4 * 64);              // 384 KB
    // total ~53 MB

    if (ws_size < off) {
        k_sentinel<<<4, 256, 0, stream>>>(out);
        return;
    }

    auto cvt = [&](const float* s, uint16_t* dmem, int n) {
        int n4 = n / 4;
        k_cvt<<<(n4 + 255) / 256, 256, 0, stream>>>(s, dmem, n4);
    };
    cvt(wih0, wih0_bf, 196608);
    cvt(wihL, wihL_bf, 1572864);
    cvt(whh, whh_bf, 1179648);
    cvt(la_w1, law1_bf, 73728);
    cvt(sa_w1, saw1_bf, 32768);
    // zero produced+consumed (contiguous: 2 * 98304 ints = 49152 float4)
    k_zero<<<192, 256, 0, stream>>>((float*)produced, 49152);

    k_encoder<<<dim3(256, 4), 256, 0, stream>>>(x, enc_w, enc_b, enc_bf);

    k_scan<<<224, BTH, 0, stream>>>(enc_bf, wih0_bf, wihL_bf, whh_bf,
                                    bih, bhh, law1_bf, la_b1, la_w2, la_b2,
                                    saw1_bf, sa_b1, sa_w2, sa_b2,
                                    ln_g, ln_b, fc_w, fc_b,
                                    ring, produced, consumed, out);
}